// Round 1
// baseline (2631.543 us; speedup 1.0000x reference)
//
#include <hip/hip_runtime.h>
#include <hip/hip_bf16.h>
#include <cstdint>
#include <cstddef>

#define EPSBN 1e-5f

// Problem constants
// B=64, CIN=256, HID=256, COUT=10, MULTI=3, KS=3, TH=TW=7, SH=SW=31

// ---------------------------------------------------------------------------
// Transpose W[OC][K] -> Wt[K][OC] so GEMM B-tile staging is coalesced.
// ---------------------------------------------------------------------------
__global__ void transpose_w_kernel(const float* __restrict__ W,
                                   float* __restrict__ Wt, int OC, int K) {
    int i = blockIdx.x * 256 + threadIdx.x;
    if (i < OC * K) {
        int oc = i / K;
        int k = i - oc * K;
        Wt[k * OC + oc] = W[i];
    }
}

// ---------------------------------------------------------------------------
// Implicit-im2col SGEMM conv.
//   out[b][oc][y][x] = epi( sum_{cin,ky,kx} in[b][cin][y+ky][x+kx] * W[oc][cin,ky,kx] )
// A = im2col [M = B*OH*OW][K],  B = Wt [K][OC]
// Tile: BM=BN=128, BK=8, 256 threads, 8x8 per thread (FMA:LDS = 4:1).
// MODE 0: BN+ReLU, 1: BN, 2: +bias
// ---------------------------------------------------------------------------
template <int KHW, int MODE>
__global__ __launch_bounds__(256) void conv_gemm(
    const float* __restrict__ in, const float* __restrict__ Wt,
    const float* __restrict__ bnp, float* __restrict__ out, int Cin, int H,
    int W, int OH, int OW, int OC, int M) {
    const int K = Cin * KHW;
    const int HW = H * W;
    const int OHW = OH * OW;

    __shared__ float As[8][128];
    __shared__ float Bs[8][128];

    const int tid = threadIdx.x;
    const int tx = tid & 15;
    const int ty = tid >> 4;
    const int m0 = blockIdx.x * 128;
    const int n0 = blockIdx.y * 128;

    // Precompute per-slot im2col base addresses (hoisted out of K loop).
    int a_base[4];
#pragma unroll
    for (int t = 0; t < 4; ++t) {
        int idx = tid + t * 256;
        int pp = idx & 127;
        int m = m0 + pp;
        if (m < M) {
            int b = m / OHW;
            int r = m - b * OHW;
            int y = r / OW;
            int x = r - y * OW;
            a_base[t] = ((b * Cin) * H + y) * W + x;
        } else {
            a_base[t] = -1;
        }
    }

    float acc[8][8];
#pragma unroll
    for (int i = 0; i < 8; ++i)
#pragma unroll
        for (int j = 0; j < 8; ++j) acc[i][j] = 0.f;

    for (int k0 = 0; k0 < K; k0 += 8) {
        // Stage A (im2col) tile: 8 x 128
#pragma unroll
        for (int t = 0; t < 4; ++t) {
            int idx = tid + t * 256;
            int j = idx >> 7;
            int pp = idx & 127;
            int k = k0 + j;
            float v = 0.f;
            if (a_base[t] >= 0) {
                int off;
                if (KHW == 9) {
                    int cin = k / 9;
                    int rem = k - cin * 9;
                    int ky = rem / 3;
                    int kx = rem - ky * 3;
                    off = a_base[t] + cin * HW + ky * W + kx;
                } else {
                    off = a_base[t] + k * HW;
                }
                v = in[off];
            }
            As[j][pp] = v;
        }
        // Stage B (weights) tile: 8 x 128 (coalesced over oc)
#pragma unroll
        for (int t = 0; t < 4; ++t) {
            int idx = tid + t * 256;
            int j = idx >> 7;
            int occ = idx & 127;
            int oc = n0 + occ;
            float v = 0.f;
            if (oc < OC) v = Wt[(size_t)(k0 + j) * OC + oc];
            Bs[j][occ] = v;
        }
        __syncthreads();
#pragma unroll
        for (int kk = 0; kk < 8; ++kk) {
            float4 a0 = *(const float4*)&As[kk][tx * 4];
            float4 a1 = *(const float4*)&As[kk][64 + tx * 4];
            float4 b0 = *(const float4*)&Bs[kk][ty * 4];
            float4 b1 = *(const float4*)&Bs[kk][64 + ty * 4];
            float av[8] = {a0.x, a0.y, a0.z, a0.w, a1.x, a1.y, a1.z, a1.w};
            float bv[8] = {b0.x, b0.y, b0.z, b0.w, b1.x, b1.y, b1.z, b1.w};
#pragma unroll
            for (int i = 0; i < 8; ++i)
#pragma unroll
                for (int j = 0; j < 8; ++j)
                    acc[i][j] = fmaf(av[i], bv[j], acc[i][j]);
        }
        __syncthreads();
    }

    // Epilogue: BN / ReLU / bias
    float sc[8], sh[8];
#pragma unroll
    for (int j = 0; j < 8; ++j) {
        int oc = n0 + ty * 4 + (j & 3) + ((j >> 2) * 64);
        float scale = 0.f, shift = 0.f;
        if (oc < OC) {
            if (MODE == 2) {
                scale = 1.f;
                shift = bnp[oc];
            } else {
                float g = bnp[oc];
                float bb = bnp[OC + oc];
                float mm = bnp[2 * OC + oc];
                float vv = bnp[3 * OC + oc];
                float inv = g * rsqrtf(vv + EPSBN);
                scale = inv;
                shift = bb - mm * inv;
            }
        }
        sc[j] = scale;
        sh[j] = shift;
    }
#pragma unroll
    for (int i = 0; i < 8; ++i) {
        int m = m0 + tx * 4 + (i & 3) + ((i >> 2) * 64);
        if (m < M) {
            int b = m / OHW;
            int r = m - b * OHW;
            size_t obase = (size_t)b * OC * OHW + r;
#pragma unroll
            for (int j = 0; j < 8; ++j) {
                int oc = n0 + ty * 4 + (j & 3) + ((j >> 2) * 64);
                if (oc < OC) {
                    float v = acc[i][j] * sc[j] + sh[j];
                    if (MODE == 0) v = fmaxf(v, 0.f);
                    out[obase + (size_t)oc * OHW] = v;
                }
            }
        }
    }
}

// ---------------------------------------------------------------------------
// Multi-scale depthwise xcorr.
// s: (64,256,29,29), k: (64,256,5,5) -> feat: (64, 3*256, 25,25)
// feat[b][i*256+c][y][x] = sum_{dy,dx in [0,5-2i)} s[b][c][y+i+dy][x+i+dx]*k[b][c][i+dy][i+dx]
// One block per (b,c); s-plane + k-plane staged in LDS.
// ---------------------------------------------------------------------------
__global__ __launch_bounds__(256) void xcorr_kernel(
    const float* __restrict__ s, const float* __restrict__ k,
    float* __restrict__ feat) {
    int bc = blockIdx.x;  // b*256 + c
    __shared__ float ss[841];
    __shared__ float kk[25];
    const float* sp = s + (size_t)bc * 841;
    const float* kp = k + (size_t)bc * 25;
    for (int i = threadIdx.x; i < 841; i += 256) ss[i] = sp[i];
    if (threadIdx.x < 25) kk[threadIdx.x] = kp[threadIdx.x];
    __syncthreads();
    int b = bc >> 8;
    int c = bc & 255;
    for (int i = 0; i < 3; ++i) {
        int ksz = 5 - 2 * i;
        float* op = feat + (size_t)(b * 768 + i * 256 + c) * 625;
        for (int p = threadIdx.x; p < 625; p += 256) {
            int y = p / 25;
            int x = p - y * 25;
            float acc = 0.f;
            for (int dy = 0; dy < ksz; ++dy)
                for (int dx = 0; dx < ksz; ++dx)
                    acc = fmaf(ss[(y + i + dy) * 29 + (x + i + dx)],
                               kk[(i + dy) * 5 + (i + dx)], acc);
            op[p] = acc;
        }
    }
}

// ---------------------------------------------------------------------------
extern "C" void kernel_launch(void* const* d_in, const int* in_sizes, int n_in,
                              void* d_out, int out_size, void* d_ws,
                              size_t ws_size, hipStream_t stream) {
    const float* kernel_in = (const float*)d_in[0];  // (64,256,7,7)
    const float* search_in = (const float*)d_in[1];  // (64,256,31,31)
    const float* wk = (const float*)d_in[2];         // (256,256,3,3)
    const float* bnk = (const float*)d_in[3];        // (4,256)
    const float* ws = (const float*)d_in[4];         // (256,256,3,3)
    const float* bns = (const float*)d_in[5];        // (4,256)
    const float* wd = (const float*)d_in[6];         // (256,768,1,1)
    const float* bnd = (const float*)d_in[7];        // (4,256)
    const float* wh1 = (const float*)d_in[8];        // (256,256,1,1)
    const float* bnh = (const float*)d_in[9];        // (4,256)
    const float* wh2 = (const float*)d_in[10];       // (10,256,1,1)
    const float* bh2 = (const float*)d_in[11];       // (10,)
    float* out = (float*)d_out;                      // (64,10,25,25)

    float* wsp = (float*)d_ws;
    size_t off = 0;
    auto alloc = [&](size_t n) {
        float* p = wsp + off;
        off += n;
        return p;
    };
    float* wkT = alloc((size_t)2304 * 256);
    float* wsT = alloc((size_t)2304 * 256);
    float* wdT = alloc((size_t)768 * 256);
    float* wh1T = alloc((size_t)256 * 256);
    float* wh2T = alloc((size_t)256 * 10);
    float* kbuf = alloc((size_t)64 * 256 * 25);     // k features (64,256,5,5)
    float* sbuf = alloc((size_t)64 * 256 * 841);    // s features (64,256,29,29)
    float* feat = alloc((size_t)64 * 768 * 625);    // xcorr out (64,768,25,25)
    float* f2 = sbuf;    // (64,256,625) aliases sbuf (s dead after xcorr)
    float* hbuf = feat;  // (64,256,625) aliases feat (feat dead after wd conv)

    // Weight transposes (tiny)
    auto tr = [&](const float* Wsrc, float* Wt, int OC, int K) {
        int n = OC * K;
        transpose_w_kernel<<<dim3((n + 255) / 256), dim3(256), 0, stream>>>(
            Wsrc, Wt, OC, K);
    };
    tr(wk, wkT, 256, 2304);
    tr(ws, wsT, 256, 2304);
    tr(wd, wdT, 256, 768);
    tr(wh1, wh1T, 256, 256);
    tr(wh2, wh2T, 10, 256);

    // 1) kernel branch: conv3x3+BN+ReLU  (M = 64*25 = 1600)
    conv_gemm<9, 0><<<dim3(13, 2), dim3(256), 0, stream>>>(
        kernel_in, wkT, bnk, kbuf, 256, 7, 7, 5, 5, 256, 1600);
    // 2) search branch: conv3x3+BN+ReLU (M = 64*841 = 53824)
    conv_gemm<9, 0><<<dim3(421, 2), dim3(256), 0, stream>>>(
        search_in, wsT, bns, sbuf, 256, 31, 31, 29, 29, 256, 53824);
    // 3) multi depthwise xcorr
    xcorr_kernel<<<dim3(64 * 256), dim3(256), 0, stream>>>(sbuf, kbuf, feat);
    // 4) 1x1 conv 768->256 + BN  (M = 64*625 = 40000)
    conv_gemm<1, 1><<<dim3(313, 2), dim3(256), 0, stream>>>(
        feat, wdT, bnd, f2, 768, 25, 25, 25, 25, 256, 40000);
    // 5) 1x1 conv 256->256 + BN + ReLU
    conv_gemm<1, 0><<<dim3(313, 2), dim3(256), 0, stream>>>(
        f2, wh1T, bnh, hbuf, 256, 25, 25, 25, 25, 256, 40000);
    // 6) 1x1 conv 256->10 + bias
    conv_gemm<1, 2><<<dim3(313, 1), dim3(256), 0, stream>>>(
        hbuf, wh2T, bh2, out, 256, 25, 25, 25, 25, 10, 40000);
}

// Round 2
// 648.295 us; speedup vs baseline: 4.0592x; 4.0592x over previous
//
#include <hip/hip_runtime.h>
#include <hip/hip_bf16.h>
#include <cstdint>
#include <cstddef>

#define EPSBN 1e-5f

typedef unsigned short u16;
typedef unsigned int u32;
typedef __bf16 bf16x8 __attribute__((ext_vector_type(8)));
typedef float f32x4 __attribute__((ext_vector_type(4)));

// ---------------------------------------------------------------------------
// fp32 -> bf16 RNE + split helpers
// ---------------------------------------------------------------------------
__device__ __forceinline__ u16 f2bf(float v) {
    u32 u = __float_as_uint(v);
    u32 r = (u + 0x7fffu + ((u >> 16) & 1u)) >> 16;
    return (u16)r;
}
__device__ __forceinline__ float bf2f(u16 h) {
    return __uint_as_float(((u32)h) << 16);
}
__device__ __forceinline__ void split_bf16(float v, u16& hi, u16& lo) {
    hi = f2bf(v);
    lo = f2bf(v - bf2f(hi));
}

// async global->LDS, 16B per lane
__device__ __forceinline__ void async_copy16(void* lds, const void* g) {
    __builtin_amdgcn_global_load_lds(
        (const __attribute__((address_space(1))) u32*)g,
        (__attribute__((address_space(3))) u32*)lds, 16, 0, 0);
}

// ---------------------------------------------------------------------------
// NCHW fp32 -> NHWC bf16 hi/lo (tiled transpose). C multiple of 64.
// ---------------------------------------------------------------------------
__global__ __launch_bounds__(256) void trans_split_act(
    const float* __restrict__ in, u16* __restrict__ hi, u16* __restrict__ lo,
    int C, int HW) {
    __shared__ float tile[64][65];
    int b = blockIdx.x;
    int c0 = blockIdx.y * 64;
    int h0 = blockIdx.z * 64;
    int cl = threadIdx.x >> 6;   // 0..3
    int hl = threadIdx.x & 63;
    for (int r = cl; r < 64; r += 4) {
        int hw = h0 + hl;
        tile[r][hl] = (hw < HW) ? in[(size_t)(b * C + c0 + r) * HW + hw] : 0.f;
    }
    __syncthreads();
    int c = threadIdx.x & 63;
    for (int r = cl; r < 64; r += 4) {
        int hw = h0 + r;
        if (hw < HW) {
            float v = tile[c][r];
            size_t o = ((size_t)b * HW + hw) * C + c0 + c;
            u16 h, l;
            split_bf16(v, h, l);
            hi[o] = h;
            lo[o] = l;
        }
    }
}

// ---------------------------------------------------------------------------
// Straight bf16 split (weights already [oc][k] contiguous)
// ---------------------------------------------------------------------------
__global__ void split_w_kernel(const float* __restrict__ in,
                               u16* __restrict__ hi, u16* __restrict__ lo,
                               int n) {
    int i = blockIdx.x * 256 + threadIdx.x;
    if (i < n) {
        u16 h, l;
        split_bf16(in[i], h, l);
        hi[i] = h;
        lo[i] = l;
    }
}

// OIHW (oc,cin,3,3) -> [oc][(ky*3+kx)*Cin + cin] bf16 pair
__global__ void perm_split_w33(const float* __restrict__ in,
                               u16* __restrict__ hi, u16* __restrict__ lo,
                               int OCn, int Cin) {
    int i = blockIdx.x * 256 + threadIdx.x;
    int n = OCn * Cin * 9;
    if (i < n) {
        int oc = i / (Cin * 9);
        int r = i - oc * (Cin * 9);
        int pos = r / Cin;
        int cin = r - pos * Cin;
        float v = in[(size_t)(oc * Cin + cin) * 9 + pos];
        u16 h, l;
        split_bf16(v, h, l);
        hi[i] = h;
        lo[i] = l;
    }
}

// ---------------------------------------------------------------------------
// Split-bf16 MFMA GEMM with implicit im2col (VALID conv, NHWC activations).
// C[m][oc] = epi( sum_k A[m][k] * W[oc][k] ),  k = (ky,kx,cin)
// BM=BN=128, BK=32, 256 threads (4 waves, each 64x64 via 4x4 16x16x32 MFMA).
// 3 MFMA products per tile: hi*hi + lo*hi + hi*lo  (~fp32 precision).
// EPI: 0 = BN+ReLU -> f32 NHWC; 1 = BN -> bf16 pair NHWC;
//      2 = BN+ReLU -> bf16 pair NHWC; 3 = +bias -> f32 NCHW.
// ---------------------------------------------------------------------------
template <int KHW, int EPI>
__global__ __launch_bounds__(256, 2) void mfma_gemm(
    const u16* __restrict__ Ahi, const u16* __restrict__ Alo,
    const u16* __restrict__ Bhi, const u16* __restrict__ Blo,
    const float* __restrict__ bnp, float* __restrict__ outF,
    u16* __restrict__ oHi, u16* __restrict__ oLo, int M, int OC, int C, int H,
    int W, int OH, int OW) {
    const int Ktot = KHW * C;
    const int nKb = Ktot >> 5;
    __shared__ u16 sAhi[128 * 32];
    __shared__ u16 sAlo[128 * 32];
    __shared__ u16 sBhi[128 * 32];
    __shared__ u16 sBlo[128 * 32];

    const int tid = threadIdx.x;
    const int n0 = blockIdx.x * 128;  // oc block
    const int m0 = blockIdx.y * 128;  // m block
    const int OHW = OH * OW;

    // Per-thread staging addresses (2 slots of 256 lanes cover a 8KB tile)
    int abase[2];
    size_t bbase[2];
    int ldsoff[2];
#pragma unroll
    for (int s = 0; s < 2; ++s) {
        int idx = tid + s * 256;
        int ml = idx >> 2;
        int kq = idx & 3;
        int m = m0 + ml;
        if (m >= M) m = M - 1;
        int b = m / OHW;
        int r = m - b * OHW;
        int y = r / OW;
        int x = r - y * OW;
        abase[s] = ((b * H + y) * W + x) * C + kq * 8;
        int oc = n0 + ml;
        if (oc >= OC) oc = OC - 1;
        bbase[s] = (size_t)oc * Ktot + kq * 8;
        ldsoff[s] = idx * 8;
    }

    f32x4 acc[4][4];
#pragma unroll
    for (int i = 0; i < 4; ++i)
#pragma unroll
        for (int j = 0; j < 4; ++j) acc[i][j] = (f32x4)0.f;

    const int lane = tid & 63;
    const int row = lane & 15;
    const int quad = lane >> 4;
    const int wv = tid >> 6;
    const int wm = (wv & 1) * 64;
    const int wn = (wv >> 1) * 64;

    for (int kb = 0; kb < nKb; ++kb) {
        int koff;
        if (KHW == 9) {
            // C == 256 here: 8 sub-blocks of 32 channels per (ky,kx)
            int pos = kb >> 3;
            int cin0 = (kb & 7) << 5;
            int ky = pos / 3;
            int kx = pos - ky * 3;
            koff = (ky * W + kx) * C + cin0;
        } else {
            koff = kb << 5;
        }
        int bko = kb << 5;
#pragma unroll
        for (int s = 0; s < 2; ++s) {
            async_copy16(&sAhi[ldsoff[s]], Ahi + abase[s] + koff);
            async_copy16(&sAlo[ldsoff[s]], Alo + abase[s] + koff);
            async_copy16(&sBhi[ldsoff[s]], Bhi + bbase[s] + bko);
            async_copy16(&sBlo[ldsoff[s]], Blo + bbase[s] + bko);
        }
        __syncthreads();

        bf16x8 afh[4], afl[4], bfh[4], bfl[4];
#pragma unroll
        for (int i = 0; i < 4; ++i) {
            int off = (wm + i * 16 + row) * 32 + quad * 8;
            afh[i] = *(const bf16x8*)&sAhi[off];
            afl[i] = *(const bf16x8*)&sAlo[off];
        }
#pragma unroll
        for (int j = 0; j < 4; ++j) {
            int off = (wn + j * 16 + row) * 32 + quad * 8;
            bfh[j] = *(const bf16x8*)&sBhi[off];
            bfl[j] = *(const bf16x8*)&sBlo[off];
        }
#pragma unroll
        for (int i = 0; i < 4; ++i)
#pragma unroll
            for (int j = 0; j < 4; ++j) {
                acc[i][j] = __builtin_amdgcn_mfma_f32_16x16x32_bf16(
                    afh[i], bfh[j], acc[i][j], 0, 0, 0);
                acc[i][j] = __builtin_amdgcn_mfma_f32_16x16x32_bf16(
                    afl[i], bfh[j], acc[i][j], 0, 0, 0);
                acc[i][j] = __builtin_amdgcn_mfma_f32_16x16x32_bf16(
                    afh[i], bfl[j], acc[i][j], 0, 0, 0);
            }
        __syncthreads();
    }

    // Epilogue. C/D layout: col(n) = lane&15, row(m) = quad*4 + reg.
#pragma unroll
    for (int j = 0; j < 4; ++j) {
        int oc = n0 + wn + j * 16 + row;
        bool ocv = oc < OC;
        float scale = 1.f, shift = 0.f;
        if (ocv) {
            if (EPI <= 2) {
                float g = bnp[oc];
                float bb = bnp[OC + oc];
                float mm = bnp[2 * OC + oc];
                float vv = bnp[3 * OC + oc];
                float inv = g * rsqrtf(vv + EPSBN);
                scale = inv;
                shift = bb - mm * inv;
            } else {
                shift = bnp[oc];  // bias
            }
        }
#pragma unroll
        for (int i = 0; i < 4; ++i) {
#pragma unroll
            for (int r = 0; r < 4; ++r) {
                int m = m0 + wm + i * 16 + quad * 4 + r;
                if (m < M && ocv) {
                    float v = acc[i][j][r] * scale + shift;
                    if (EPI == 0 || EPI == 2) v = fmaxf(v, 0.f);
                    if (EPI == 0) {
                        outF[(size_t)m * OC + oc] = v;
                    } else if (EPI == 3) {
                        int b = m / OHW;
                        int rr = m - b * OHW;
                        outF[((size_t)b * OC + oc) * OHW + rr] = v;
                    } else {
                        u16 h, l;
                        split_bf16(v, h, l);
                        oHi[(size_t)m * OC + oc] = h;
                        oLo[(size_t)m * OC + oc] = l;
                    }
                }
            }
        }
    }
}

// ---------------------------------------------------------------------------
// Multi-scale depthwise xcorr, NHWC fp32 in, bf16-pair NHWC out.
// s: [64][29][29][256], k: [64][5][5][256] -> feat: [64][25][25][768]
// Block per (b,y); thread per channel c. k taps live in 25 VGPRs.
// ---------------------------------------------------------------------------
__global__ __launch_bounds__(256) void xcorr_nhwc(
    const float* __restrict__ sf, const float* __restrict__ kf,
    u16* __restrict__ fhi, u16* __restrict__ flo) {
    int by = blockIdx.x;  // b*25 + y
    int b = by / 25;
    int y = by - b * 25;
    int c = threadIdx.x;  // 0..255
    float kv[25];
#pragma unroll
    for (int p = 0; p < 25; ++p)
        kv[p] = kf[(size_t)(b * 25 + p) * 256 + c];
    const float* srow = sf + (size_t)(b * 29 + y) * 29 * 256 + c;
    for (int x = 0; x < 25; ++x) {
        float sv[25];
#pragma unroll
        for (int d = 0; d < 5; ++d)
#pragma unroll
            for (int e = 0; e < 5; ++e)
                sv[d * 5 + e] = srow[(size_t)(d * 29 + x + e) * 256];
        float a0 = 0.f, a1 = 0.f, a2;
#pragma unroll
        for (int p = 0; p < 25; ++p) a0 = fmaf(sv[p], kv[p], a0);
#pragma unroll
        for (int d = 1; d < 4; ++d)
#pragma unroll
            for (int e = 1; e < 4; ++e)
                a1 = fmaf(sv[d * 5 + e], kv[d * 5 + e], a1);
        a2 = sv[12] * kv[12];
        size_t m = (size_t)by * 25 + x;
        size_t o = m * 768 + c;
        u16 h, l;
        split_bf16(a0, h, l);
        fhi[o] = h;
        flo[o] = l;
        split_bf16(a1, h, l);
        fhi[o + 256] = h;
        flo[o + 256] = l;
        split_bf16(a2, h, l);
        fhi[o + 512] = h;
        flo[o + 512] = l;
    }
}

// ---------------------------------------------------------------------------
extern "C" void kernel_launch(void* const* d_in, const int* in_sizes, int n_in,
                              void* d_out, int out_size, void* d_ws,
                              size_t ws_size, hipStream_t stream) {
    const float* kernel_in = (const float*)d_in[0];  // (64,256,7,7)
    const float* search_in = (const float*)d_in[1];  // (64,256,31,31)
    const float* wk = (const float*)d_in[2];         // (256,256,3,3)
    const float* bnk = (const float*)d_in[3];
    const float* ws = (const float*)d_in[4];
    const float* bns = (const float*)d_in[5];
    const float* wd = (const float*)d_in[6];   // (256,768)
    const float* bnd = (const float*)d_in[7];
    const float* wh1 = (const float*)d_in[8];  // (256,256)
    const float* bnh = (const float*)d_in[9];
    const float* wh2 = (const float*)d_in[10];  // (10,256)
    const float* bh2 = (const float*)d_in[11];  // (10,)
    float* out = (float*)d_out;                 // (64,10,25,25) NCHW

    char* base = (char*)d_ws;
    size_t off = 0;
    auto alloc = [&](size_t bytes) {
        off = (off + 511) & ~(size_t)511;
        void* p = base + off;
        off += bytes;
        return p;
    };

    // Persistent-ish region (live across the whole pipeline)
    u16* wdT_hi = (u16*)alloc(768 * 256 * 2);
    u16* wdT_lo = (u16*)alloc(768 * 256 * 2);
    u16* wh1T_hi = (u16*)alloc(256 * 256 * 2);
    u16* wh1T_lo = (u16*)alloc(256 * 256 * 2);
    u16* wh2T_hi = (u16*)alloc(10 * 256 * 2);
    u16* wh2T_lo = (u16*)alloc(10 * 256 * 2);
    size_t Pf = (off + 511) & ~(size_t)511;        // f2 later aliases here
    float* kfeat = (float*)alloc((size_t)1600 * 256 * 4);
    float* sfeat = (float*)alloc((size_t)53824 * 256 * 4);
    size_t P1 = (off + 511) & ~(size_t)511;        // feat/hbuf alias here
    // Transient group (dead after conv-k/conv-s)
    u16* wkT_hi = (u16*)alloc((size_t)2304 * 256 * 2);
    u16* wkT_lo = (u16*)alloc((size_t)2304 * 256 * 2);
    u16* wsT_hi = (u16*)alloc((size_t)2304 * 256 * 2);
    u16* wsT_lo = (u16*)alloc((size_t)2304 * 256 * 2);
    u16* ka_hi = (u16*)alloc((size_t)64 * 49 * 256 * 2);
    u16* ka_lo = (u16*)alloc((size_t)64 * 49 * 256 * 2);
    u16* sa_hi = (u16*)alloc((size_t)64 * 961 * 256 * 2);
    u16* sa_lo = (u16*)alloc((size_t)64 * 961 * 256 * 2);
    // Aliased buffers
    u16* feat_hi = (u16*)(base + P1);                       // 64*625*768
    u16* feat_lo = feat_hi + (size_t)64 * 625 * 768;
    u16* f2_hi = (u16*)(base + Pf);                         // 40000*256
    u16* f2_lo = f2_hi + (size_t)40000 * 256;
    u16* h_hi = (u16*)(base + P1);                          // 40000*256
    u16* h_lo = h_hi + (size_t)40000 * 256;

    // --- conversions ---
    trans_split_act<<<dim3(64, 4, 16), 256, 0, stream>>>(search_in, sa_hi,
                                                         sa_lo, 256, 961);
    trans_split_act<<<dim3(64, 4, 1), 256, 0, stream>>>(kernel_in, ka_hi,
                                                        ka_lo, 256, 49);
    {
        int n = 2304 * 256;
        perm_split_w33<<<(n + 255) / 256, 256, 0, stream>>>(wk, wkT_hi, wkT_lo,
                                                            256, 256);
        perm_split_w33<<<(n + 255) / 256, 256, 0, stream>>>(ws, wsT_hi, wsT_lo,
                                                            256, 256);
    }
    split_w_kernel<<<(768 * 256 + 255) / 256, 256, 0, stream>>>(
        wd, wdT_hi, wdT_lo, 768 * 256);
    split_w_kernel<<<(256 * 256 + 255) / 256, 256, 0, stream>>>(
        wh1, wh1T_hi, wh1T_lo, 256 * 256);
    split_w_kernel<<<(10 * 256 + 255) / 256, 256, 0, stream>>>(
        wh2, wh2T_hi, wh2T_lo, 10 * 256);

    // --- GEMM pipeline ---
    // conv-k: 3x3, M=1600, K=2304 -> kfeat f32 NHWC
    mfma_gemm<9, 0><<<dim3(2, 13), 256, 0, stream>>>(
        ka_hi, ka_lo, wkT_hi, wkT_lo, bnk, kfeat, nullptr, nullptr, 1600, 256,
        256, 7, 7, 5, 5);
    // conv-s: 3x3, M=53824, K=2304 -> sfeat f32 NHWC
    mfma_gemm<9, 0><<<dim3(2, 421), 256, 0, stream>>>(
        sa_hi, sa_lo, wsT_hi, wsT_lo, bns, sfeat, nullptr, nullptr, 53824, 256,
        256, 31, 31, 29, 29);
    // xcorr -> feat bf16 pair NHWC [40000][768]
    xcorr_nhwc<<<dim3(1600), 256, 0, stream>>>(sfeat, kfeat, feat_hi, feat_lo);
    // wd: 1x1, K=768, BN -> f2 pair
    mfma_gemm<1, 1><<<dim3(2, 313), 256, 0, stream>>>(
        feat_hi, feat_lo, wdT_hi, wdT_lo, bnd, nullptr, f2_hi, f2_lo, 40000,
        256, 768, 25, 25, 25, 25);
    // wh1: 1x1, K=256, BN+ReLU -> h pair
    mfma_gemm<1, 2><<<dim3(2, 313), 256, 0, stream>>>(
        f2_hi, f2_lo, wh1T_hi, wh1T_lo, bnh, nullptr, h_hi, h_lo, 40000, 256,
        256, 25, 25, 25, 25);
    // wh2: 1x1, K=256, +bias -> out f32 NCHW
    mfma_gemm<1, 3><<<dim3(1, 313), 256, 0, stream>>>(
        h_hi, h_lo, wh2T_hi, wh2T_lo, bh2, out, nullptr, nullptr, 40000, 10,
        256, 25, 25, 25, 25);
}

// Round 3
// 560.644 us; speedup vs baseline: 4.6938x; 1.1563x over previous
//
#include <hip/hip_runtime.h>
#include <hip/hip_bf16.h>
#include <cstdint>
#include <cstddef>

#define EPSBN 1e-5f

typedef unsigned short u16;
typedef unsigned int u32;
typedef __bf16 bf16x8 __attribute__((ext_vector_type(8)));
typedef float f32x4 __attribute__((ext_vector_type(4)));

// ---------------------------------------------------------------------------
// fp32 -> bf16 RNE + split helpers
// ---------------------------------------------------------------------------
__device__ __forceinline__ u16 f2bf(float v) {
    u32 u = __float_as_uint(v);
    u32 r = (u + 0x7fffu + ((u >> 16) & 1u)) >> 16;
    return (u16)r;
}
__device__ __forceinline__ float bf2f(u16 h) {
    return __uint_as_float(((u32)h) << 16);
}
__device__ __forceinline__ void split_bf16(float v, u16& hi, u16& lo) {
    hi = f2bf(v);
    lo = f2bf(v - bf2f(hi));
}

// async global->LDS, 16B per lane
__device__ __forceinline__ void async_copy16(void* lds, const void* g) {
    __builtin_amdgcn_global_load_lds(
        (const __attribute__((address_space(1))) u32*)g,
        (__attribute__((address_space(3))) u32*)lds, 16, 0, 0);
}

// ---------------------------------------------------------------------------
// NCHW fp32 -> NHWC bf16 hi/lo for BOTH activations (z=16 -> kernel input).
// ---------------------------------------------------------------------------
__global__ __launch_bounds__(256) void trans_split_all(
    const float* __restrict__ sin, u16* __restrict__ shi,
    u16* __restrict__ slo, const float* __restrict__ kin,
    u16* __restrict__ khi, u16* __restrict__ klo) {
    __shared__ float tile[64][65];
    int b = blockIdx.x;
    int c0 = blockIdx.y * 64;
    bool isk = (blockIdx.z == 16);
    const float* in = isk ? kin : sin;
    u16* hi = isk ? khi : shi;
    u16* lo = isk ? klo : slo;
    int HW = isk ? 49 : 961;
    int h0 = isk ? 0 : blockIdx.z * 64;
    int cl = threadIdx.x >> 6;  // 0..3
    int hl = threadIdx.x & 63;
    for (int r = cl; r < 64; r += 4) {
        int hw = h0 + hl;
        tile[r][hl] =
            (hw < HW) ? in[(size_t)(b * 256 + c0 + r) * HW + hw] : 0.f;
    }
    __syncthreads();
    int c = threadIdx.x & 63;
    for (int r = cl; r < 64; r += 4) {
        int hw = h0 + r;
        if (hw < HW) {
            float v = tile[c][r];
            size_t o = ((size_t)b * HW + hw) * 256 + c0 + c;
            u16 h, l;
            split_bf16(v, h, l);
            hi[o] = h;
            lo[o] = l;
        }
    }
}

// ---------------------------------------------------------------------------
// All weight preps in one ranged launch.
//  blocks [0,2304)      : wk  OIHW->[oc][(ky*3+kx)*256+cin] split
//  blocks [2304,4608)   : ws  same
//  blocks [4608,5376)   : wd  straight split (196608 elems)
//  blocks [5376,5632)   : wh1 straight split (65536)
//  blocks [5632,5642)   : wh2 straight split (2560)
// ---------------------------------------------------------------------------
__device__ __forceinline__ void perm33_one(const float* in, u16* hi, u16* lo,
                                           int i) {
    int oc = i / (256 * 9);
    int r = i - oc * (256 * 9);
    int pos = r / 256;
    int cin = r - pos * 256;
    float v = in[(size_t)(oc * 256 + cin) * 9 + pos];
    u16 h, l;
    split_bf16(v, h, l);
    hi[i] = h;
    lo[i] = l;
}
__global__ __launch_bounds__(256) void prep_weights(
    const float* __restrict__ wk, const float* __restrict__ ws,
    const float* __restrict__ wd, const float* __restrict__ wh1,
    const float* __restrict__ wh2, u16* wkhi, u16* wklo, u16* wshi, u16* wslo,
    u16* wdhi, u16* wdlo, u16* wh1hi, u16* wh1lo, u16* wh2hi, u16* wh2lo) {
    int blk = blockIdx.x;
    int tid = threadIdx.x;
    if (blk < 2304) {
        perm33_one(wk, wkhi, wklo, blk * 256 + tid);
    } else if (blk < 4608) {
        perm33_one(ws, wshi, wslo, (blk - 2304) * 256 + tid);
    } else if (blk < 5376) {
        int i = (blk - 4608) * 256 + tid;
        u16 h, l;
        split_bf16(wd[i], h, l);
        wdhi[i] = h;
        wdlo[i] = l;
    } else if (blk < 5632) {
        int i = (blk - 5376) * 256 + tid;
        u16 h, l;
        split_bf16(wh1[i], h, l);
        wh1hi[i] = h;
        wh1lo[i] = l;
    } else {
        int i = (blk - 5632) * 256 + tid;
        u16 h, l;
        split_bf16(wh2[i], h, l);
        wh2hi[i] = h;
        wh2lo[i] = l;
    }
}

// ---------------------------------------------------------------------------
// Split-bf16 MFMA GEMM body, implicit im2col (VALID conv, NHWC).
// BM=BN=128, BK=32, 256 thr (4 waves, 64x64 each via 4x4 16x16x32 MFMA).
// XOR-swizzled LDS: chunk kq of row ml stored at slot kq ^ ((ml>>1)&3)
// -> ds_read_b128 spreads each quarter-wave over all 32 banks (2-way, free).
// EPI: 0 BN+ReLU->f32 NHWC; 1 BN->bf16 pair; 2 BN+ReLU->bf16 pair;
//      3 +bias->f32 NCHW.
// ---------------------------------------------------------------------------
template <int KHW, int EPI>
__device__ __forceinline__ void gemm_body(
    u16* sAhi, u16* sAlo, u16* sBhi, u16* sBlo, const u16* __restrict__ Ahi,
    const u16* __restrict__ Alo, const u16* __restrict__ Bhi,
    const u16* __restrict__ Blo, const float* __restrict__ bnp,
    float* __restrict__ outF, u16* __restrict__ oHi, u16* __restrict__ oLo,
    int m0, int n0, int M, int OC, int C, int H, int W, int OH, int OW) {
    const int Ktot = KHW * C;
    const int nKb = Ktot >> 5;
    const int tid = threadIdx.x;
    const int OHW = OH * OW;

    int abase[2];
    size_t bbase[2];
    int ldsoff[2];
#pragma unroll
    for (int s = 0; s < 2; ++s) {
        int idx = tid + s * 256;
        int ml = idx >> 2;
        int kq = (idx & 3) ^ ((ml >> 1) & 3);  // swizzled source chunk
        int m = m0 + ml;
        if (m >= M) m = M - 1;
        int b = m / OHW;
        int r = m - b * OHW;
        int y = r / OW;
        int x = r - y * OW;
        abase[s] = ((b * H + y) * W + x) * C + kq * 8;
        int oc = n0 + ml;
        if (oc >= OC) oc = OC - 1;
        bbase[s] = (size_t)oc * Ktot + kq * 8;
        ldsoff[s] = idx * 8;
    }

    f32x4 acc[4][4];
#pragma unroll
    for (int i = 0; i < 4; ++i)
#pragma unroll
        for (int j = 0; j < 4; ++j) acc[i][j] = (f32x4)0.f;

    const int lane = tid & 63;
    const int row = lane & 15;
    const int quad = lane >> 4;
    const int wv = tid >> 6;
    const int wm = (wv & 1) * 64;
    const int wn = (wv >> 1) * 64;
    const int sw = (quad ^ ((row >> 1) & 3)) * 8;  // swizzled read chunk

    for (int kb = 0; kb < nKb; ++kb) {
        int koff;
        if (KHW == 9) {
            // C == 256: 8 sub-blocks of 32 channels per (ky,kx)
            int pos = kb >> 3;
            int cin0 = (kb & 7) << 5;
            int ky = pos / 3;
            int kx = pos - ky * 3;
            koff = (ky * W + kx) * C + cin0;
        } else {
            koff = kb << 5;
        }
        int bko = kb << 5;
#pragma unroll
        for (int s = 0; s < 2; ++s) {
            async_copy16(&sAhi[ldsoff[s]], Ahi + abase[s] + koff);
            async_copy16(&sAlo[ldsoff[s]], Alo + abase[s] + koff);
            async_copy16(&sBhi[ldsoff[s]], Bhi + bbase[s] + bko);
            async_copy16(&sBlo[ldsoff[s]], Blo + bbase[s] + bko);
        }
        __syncthreads();

        bf16x8 afh[4], afl[4], bfh[4], bfl[4];
#pragma unroll
        for (int i = 0; i < 4; ++i) {
            int off = (wm + i * 16 + row) * 32 + sw;
            afh[i] = *(const bf16x8*)&sAhi[off];
            afl[i] = *(const bf16x8*)&sAlo[off];
        }
#pragma unroll
        for (int j = 0; j < 4; ++j) {
            int off = (wn + j * 16 + row) * 32 + sw;
            bfh[j] = *(const bf16x8*)&sBhi[off];
            bfl[j] = *(const bf16x8*)&sBlo[off];
        }
#pragma unroll
        for (int i = 0; i < 4; ++i)
#pragma unroll
            for (int j = 0; j < 4; ++j) {
                acc[i][j] = __builtin_amdgcn_mfma_f32_16x16x32_bf16(
                    afh[i], bfh[j], acc[i][j], 0, 0, 0);
                acc[i][j] = __builtin_amdgcn_mfma_f32_16x16x32_bf16(
                    afl[i], bfh[j], acc[i][j], 0, 0, 0);
                acc[i][j] = __builtin_amdgcn_mfma_f32_16x16x32_bf16(
                    afh[i], bfl[j], acc[i][j], 0, 0, 0);
            }
        __syncthreads();
    }

    // Epilogue. C/D layout: col(n) = lane&15, row(m) = quad*4 + reg.
#pragma unroll
    for (int j = 0; j < 4; ++j) {
        int oc = n0 + wn + j * 16 + row;
        bool ocv = oc < OC;
        float scale = 1.f, shift = 0.f;
        if (ocv) {
            if (EPI <= 2) {
                float g = bnp[oc];
                float bb = bnp[OC + oc];
                float mm = bnp[2 * OC + oc];
                float vv = bnp[3 * OC + oc];
                float inv = g * rsqrtf(vv + EPSBN);
                scale = inv;
                shift = bb - mm * inv;
            } else {
                shift = bnp[oc];  // bias
            }
        }
#pragma unroll
        for (int i = 0; i < 4; ++i) {
#pragma unroll
            for (int r = 0; r < 4; ++r) {
                int m = m0 + wm + i * 16 + quad * 4 + r;
                if (m < M && ocv) {
                    float v = acc[i][j][r] * scale + shift;
                    if (EPI == 0 || EPI == 2) v = fmaxf(v, 0.f);
                    if (EPI == 0) {
                        outF[(size_t)m * OC + oc] = v;
                    } else if (EPI == 3) {
                        int b = m / OHW;
                        int rr = m - b * OHW;
                        outF[((size_t)b * OC + oc) * OHW + rr] = v;
                    } else {
                        u16 h, l;
                        split_bf16(v, h, l);
                        oHi[(size_t)m * OC + oc] = h;
                        oLo[(size_t)m * OC + oc] = l;
                    }
                }
            }
        }
    }
}

// Fused conv3x3 for search (x-blocks [0,421)) and kernel (x-blocks [421,434)).
__global__ __launch_bounds__(256, 2) void conv33_fused(
    const u16* sAhi_g, const u16* sAlo_g, const u16* wsHi, const u16* wsLo,
    const float* bns, float* sOut, const u16* kAhi_g, const u16* kAlo_g,
    const u16* wkHi, const u16* wkLo, const float* bnk, float* kOut) {
    __shared__ u16 sAhi[128 * 32];
    __shared__ u16 sAlo[128 * 32];
    __shared__ u16 sBhi[128 * 32];
    __shared__ u16 sBlo[128 * 32];
    bool sec = blockIdx.x >= 421;
    const u16* Ahi = sec ? kAhi_g : sAhi_g;
    const u16* Alo = sec ? kAlo_g : sAlo_g;
    const u16* Bhi = sec ? wkHi : wsHi;
    const u16* Blo = sec ? wkLo : wsLo;
    const float* bnp = sec ? bnk : bns;
    float* outF = sec ? kOut : sOut;
    int M = sec ? 1600 : 53824;
    int H = sec ? 7 : 31;
    int OHs = sec ? 5 : 29;
    int m0 = (blockIdx.x - (sec ? 421 : 0)) * 128;
    int n0 = blockIdx.y * 128;
    gemm_body<9, 0>(sAhi, sAlo, sBhi, sBlo, Ahi, Alo, Bhi, Blo, bnp, outF,
                    nullptr, nullptr, m0, n0, M, 256, 256, H, H, OHs, OHs);
}

template <int EPI>
__global__ __launch_bounds__(256, 2) void gemm_1x1(
    const u16* __restrict__ Ahi, const u16* __restrict__ Alo,
    const u16* __restrict__ Bhi, const u16* __restrict__ Blo,
    const float* __restrict__ bnp, float* __restrict__ outF,
    u16* __restrict__ oHi, u16* __restrict__ oLo, int M, int OC, int C) {
    __shared__ u16 sAhi[128 * 32];
    __shared__ u16 sAlo[128 * 32];
    __shared__ u16 sBhi[128 * 32];
    __shared__ u16 sBlo[128 * 32];
    gemm_body<1, EPI>(sAhi, sAlo, sBhi, sBlo, Ahi, Alo, Bhi, Blo, bnp, outF,
                      oHi, oLo, blockIdx.x * 128, blockIdx.y * 128, M, OC, C,
                      25, 25, 25, 25);
}

// ---------------------------------------------------------------------------
// Multi-scale depthwise xcorr, NHWC fp32 in, bf16-pair NHWC out.
// Sliding 5x5 window: 5 fresh loads per x instead of 25.
// ---------------------------------------------------------------------------
__global__ __launch_bounds__(256) void xcorr_nhwc(
    const float* __restrict__ sf, const float* __restrict__ kf,
    u16* __restrict__ fhi, u16* __restrict__ flo) {
    int by = blockIdx.x;  // b*25 + y
    int b = by / 25;
    int y = by - b * 25;
    int c = threadIdx.x;  // 0..255
    float kv[25];
#pragma unroll
    for (int p = 0; p < 25; ++p) kv[p] = kf[(size_t)(b * 25 + p) * 256 + c];
    const float* srow = sf + (size_t)(b * 29 + y) * 29 * 256 + c;
    float sv[25];
#pragma unroll
    for (int d = 0; d < 5; ++d)
#pragma unroll
        for (int e = 0; e < 5; ++e)
            sv[d * 5 + e] = srow[(size_t)(d * 29 + e) * 256];
    for (int x = 0;; ++x) {
        float a0 = 0.f, a1 = 0.f, a2;
#pragma unroll
        for (int p = 0; p < 25; ++p) a0 = fmaf(sv[p], kv[p], a0);
#pragma unroll
        for (int d = 1; d < 4; ++d)
#pragma unroll
            for (int e = 1; e < 4; ++e)
                a1 = fmaf(sv[d * 5 + e], kv[d * 5 + e], a1);
        a2 = sv[12] * kv[12];
        size_t o = ((size_t)by * 25 + x) * 768 + c;
        u16 h, l;
        split_bf16(a0, h, l);
        fhi[o] = h;
        flo[o] = l;
        split_bf16(a1, h, l);
        fhi[o + 256] = h;
        flo[o + 256] = l;
        split_bf16(a2, h, l);
        fhi[o + 512] = h;
        flo[o + 512] = l;
        if (x == 24) break;
#pragma unroll
        for (int d = 0; d < 5; ++d) {
#pragma unroll
            for (int e = 0; e < 4; ++e) sv[d * 5 + e] = sv[d * 5 + e + 1];
            sv[d * 5 + 4] = srow[(size_t)(d * 29 + x + 5) * 256];
        }
    }
}

// ---------------------------------------------------------------------------
extern "C" void kernel_launch(void* const* d_in, const int* in_sizes, int n_in,
                              void* d_out, int out_size, void* d_ws,
                              size_t ws_size, hipStream_t stream) {
    const float* kernel_in = (const float*)d_in[0];  // (64,256,7,7)
    const float* search_in = (const float*)d_in[1];  // (64,256,31,31)
    const float* wk = (const float*)d_in[2];         // (256,256,3,3)
    const float* bnk = (const float*)d_in[3];
    const float* ws = (const float*)d_in[4];
    const float* bns = (const float*)d_in[5];
    const float* wd = (const float*)d_in[6];  // (256,768)
    const float* bnd = (const float*)d_in[7];
    const float* wh1 = (const float*)d_in[8];  // (256,256)
    const float* bnh = (const float*)d_in[9];
    const float* wh2 = (const float*)d_in[10];  // (10,256)
    const float* bh2 = (const float*)d_in[11];  // (10,)
    float* out = (float*)d_out;                 // (64,10,25,25) NCHW

    char* base = (char*)d_ws;
    size_t off = 0;
    auto alloc = [&](size_t bytes) {
        off = (off + 511) & ~(size_t)511;
        void* p = base + off;
        off += bytes;
        return p;
    };

    // Persistent region
    u16* wdT_hi = (u16*)alloc(768 * 256 * 2);
    u16* wdT_lo = (u16*)alloc(768 * 256 * 2);
    u16* wh1T_hi = (u16*)alloc(256 * 256 * 2);
    u16* wh1T_lo = (u16*)alloc(256 * 256 * 2);
    u16* wh2T_hi = (u16*)alloc(10 * 256 * 2);
    u16* wh2T_lo = (u16*)alloc(10 * 256 * 2);
    size_t Pf = (off + 511) & ~(size_t)511;  // f2 aliases here later
    float* kfeat = (float*)alloc((size_t)1600 * 256 * 4);
    float* sfeat = (float*)alloc((size_t)53824 * 256 * 4);
    size_t P1 = (off + 511) & ~(size_t)511;  // feat/hbuf alias here
    // Transients (dead after conv33_fused)
    u16* wkT_hi = (u16*)alloc((size_t)2304 * 256 * 2);
    u16* wkT_lo = (u16*)alloc((size_t)2304 * 256 * 2);
    u16* wsT_hi = (u16*)alloc((size_t)2304 * 256 * 2);
    u16* wsT_lo = (u16*)alloc((size_t)2304 * 256 * 2);
    u16* ka_hi = (u16*)alloc((size_t)64 * 49 * 256 * 2);
    u16* ka_lo = (u16*)alloc((size_t)64 * 49 * 256 * 2);
    u16* sa_hi = (u16*)alloc((size_t)64 * 961 * 256 * 2);
    u16* sa_lo = (u16*)alloc((size_t)64 * 961 * 256 * 2);
    // Aliases
    u16* feat_hi = (u16*)(base + P1);  // 64*625*768
    u16* feat_lo = feat_hi + (size_t)64 * 625 * 768;
    u16* f2_hi = (u16*)(base + Pf);  // 40000*256
    u16* f2_lo = f2_hi + (size_t)40000 * 256;
    u16* h_hi = (u16*)(base + P1);  // 40000*256
    u16* h_lo = h_hi + (size_t)40000 * 256;

    // 1) activation transpose+split (search z=0..15, kernel z=16)
    trans_split_all<<<dim3(64, 4, 17), 256, 0, stream>>>(
        search_in, sa_hi, sa_lo, kernel_in, ka_hi, ka_lo);
    // 2) all weight preps
    prep_weights<<<dim3(5642), 256, 0, stream>>>(
        wk, ws, wd, wh1, wh2, wkT_hi, wkT_lo, wsT_hi, wsT_lo, wdT_hi, wdT_lo,
        wh1T_hi, wh1T_lo, wh2T_hi, wh2T_lo);
    // 3) fused conv3x3 (search + kernel branches)
    conv33_fused<<<dim3(434, 2), 256, 0, stream>>>(
        sa_hi, sa_lo, wsT_hi, wsT_lo, bns, sfeat, ka_hi, ka_lo, wkT_hi,
        wkT_lo, bnk, kfeat);
    // 4) xcorr -> feat bf16 pair NHWC [40000][768]
    xcorr_nhwc<<<dim3(1600), 256, 0, stream>>>(sfeat, kfeat, feat_hi, feat_lo);
    // 5) wd: 1x1, K=768, BN -> f2 pair
    gemm_1x1<1><<<dim3(313, 2), 256, 0, stream>>>(feat_hi, feat_lo, wdT_hi,
                                                  wdT_lo, bnd, nullptr, f2_hi,
                                                  f2_lo, 40000, 256, 768);
    // 6) wh1: 1x1, K=256, BN+ReLU -> h pair
    gemm_1x1<2><<<dim3(313, 2), 256, 0, stream>>>(f2_hi, f2_lo, wh1T_hi,
                                                  wh1T_lo, bnh, nullptr, h_hi,
                                                  h_lo, 40000, 256, 256);
    // 7) wh2: 1x1, K=256, +bias -> out f32 NCHW
    gemm_1x1<3><<<dim3(313, 1), 256, 0, stream>>>(h_hi, h_lo, wh2T_hi,
                                                  wh2T_lo, bh2, out, nullptr,
                                                  nullptr, 40000, 10, 256);
}

// Round 4
// 508.634 us; speedup vs baseline: 5.1737x; 1.1023x over previous
//
#include <hip/hip_runtime.h>
#include <hip/hip_bf16.h>
#include <cstdint>
#include <cstddef>

#define EPSBN 1e-5f

typedef unsigned short u16;
typedef unsigned int u32;
typedef __bf16 bf16x8 __attribute__((ext_vector_type(8)));
typedef float f32x4 __attribute__((ext_vector_type(4)));

// ---------------------------------------------------------------------------
// fp32 -> bf16 RNE + split helpers
// ---------------------------------------------------------------------------
__device__ __forceinline__ u16 f2bf(float v) {
    u32 u = __float_as_uint(v);
    u32 r = (u + 0x7fffu + ((u >> 16) & 1u)) >> 16;
    return (u16)r;
}
__device__ __forceinline__ float bf2f(u16 h) {
    return __uint_as_float(((u32)h) << 16);
}
__device__ __forceinline__ void split_bf16(float v, u16& hi, u16& lo) {
    hi = f2bf(v);
    lo = f2bf(v - bf2f(hi));
}

// async global->LDS, 16B per lane
__device__ __forceinline__ void async_copy16(void* lds, const void* g) {
    __builtin_amdgcn_global_load_lds(
        (const __attribute__((address_space(1))) u32*)g,
        (__attribute__((address_space(3))) u32*)lds, 16, 0, 0);
}

// ---------------------------------------------------------------------------
// NCHW fp32 -> NHWC bf16 hi/lo for BOTH activations (z=16 -> kernel input).
// ---------------------------------------------------------------------------
__global__ __launch_bounds__(256) void trans_split_all(
    const float* __restrict__ sin, u16* __restrict__ shi,
    u16* __restrict__ slo, const float* __restrict__ kin,
    u16* __restrict__ khi, u16* __restrict__ klo) {
    __shared__ float tile[64][65];
    int b = blockIdx.x;
    int c0 = blockIdx.y * 64;
    bool isk = (blockIdx.z == 16);
    const float* in = isk ? kin : sin;
    u16* hi = isk ? khi : shi;
    u16* lo = isk ? klo : slo;
    int HW = isk ? 49 : 961;
    int h0 = isk ? 0 : blockIdx.z * 64;
    int cl = threadIdx.x >> 6;  // 0..3
    int hl = threadIdx.x & 63;
    for (int r = cl; r < 64; r += 4) {
        int hw = h0 + hl;
        tile[r][hl] =
            (hw < HW) ? in[(size_t)(b * 256 + c0 + r) * HW + hw] : 0.f;
    }
    __syncthreads();
    int c = threadIdx.x & 63;
    for (int r = cl; r < 64; r += 4) {
        int hw = h0 + r;
        if (hw < HW) {
            float v = tile[c][r];
            size_t o = ((size_t)b * HW + hw) * 256 + c0 + c;
            u16 h, l;
            split_bf16(v, h, l);
            hi[o] = h;
            lo[o] = l;
        }
    }
}

// ---------------------------------------------------------------------------
// Pack all weights into MFMA B-fragment order:
//   Bp[oct][k32][d(hi/lo)][lane][j] = W[oct*16 + (lane&15)][k32*32+(lane>>4)*8+j]
// K-order for 3x3 convs is (pos, cin): k = pos*256 + cin (matches A im2col).
// blocks: [0,2304) wk | [2304,4608) ws | [4608,5376) wd | [5376,5632) wh1 |
//         [5632,5760) wh2 (OC padded to 128, zeros beyond oc 10)
// ---------------------------------------------------------------------------
__global__ __launch_bounds__(256) void prep_frags(
    const float* __restrict__ wk, const float* __restrict__ ws,
    const float* __restrict__ wd, const float* __restrict__ wh1,
    const float* __restrict__ wh2, u16* __restrict__ bpk,
    u16* __restrict__ bps, u16* __restrict__ bpd, u16* __restrict__ bp1,
    u16* __restrict__ bp2) {
    int blk = blockIdx.x, tid = threadIdx.x;
    const float* W;
    u16* Bp;
    int nK32, OCr, K, i;
    bool conv = false;
    if (blk < 2304) {
        W = wk; Bp = bpk; nK32 = 72; OCr = 256; K = 2304; conv = true;
        i = blk * 256 + tid;
    } else if (blk < 4608) {
        W = ws; Bp = bps; nK32 = 72; OCr = 256; K = 2304; conv = true;
        i = (blk - 2304) * 256 + tid;
    } else if (blk < 5376) {
        W = wd; Bp = bpd; nK32 = 24; OCr = 256; K = 768;
        i = (blk - 4608) * 256 + tid;
    } else if (blk < 5632) {
        W = wh1; Bp = bp1; nK32 = 8; OCr = 256; K = 256;
        i = (blk - 5376) * 256 + tid;
    } else {
        W = wh2; Bp = bp2; nK32 = 8; OCr = 10; K = 256;
        i = (blk - 5632) * 256 + tid;
    }
    int per = nK32 * 512;
    int oct = i / per;
    int r = i - oct * per;
    int k32 = r >> 9;
    int lr = r & 511;
    int l = lr >> 3, j = lr & 7;
    int oc = oct * 16 + (l & 15);
    int k = k32 * 32 + ((l >> 4) << 3) + j;
    float v = 0.f;
    if (oc < OCr)
        v = conv ? W[(size_t)(oc * 256 + (k & 255)) * 9 + (k >> 8)]
                 : W[(size_t)oc * K + k];
    u16 h, lo;
    split_bf16(v, h, lo);
    size_t o = (size_t)(oct * nK32 + k32) * 1024 + lr;
    Bp[o] = h;
    Bp[o + 512] = lo;
}

// ---------------------------------------------------------------------------
// Split-bf16 MFMA GEMM: A staged in LDS (BK=64, XOR-swizzled 8-chunk rows),
// B fragments loaded straight from global (prepacked, L2-resident).
// BM=BN=128, 256 thr, 4 waves (2m x 2n), each 64x64 via 4x4 16x16x32 MFMA.
// 3 MFMA per product: hi*hi + lo*hi + hi*lo.
// EPI: 0 BN+ReLU->f32 NHWC; 1 BN->bf16 pair; 2 BN+ReLU->bf16 pair;
//      3 +bias->f32 NCHW.
// ---------------------------------------------------------------------------
template <int KHW, int EPI>
__device__ __forceinline__ void gemm_body(
    u16* sA, const u16* __restrict__ Ahi, const u16* __restrict__ Alo,
    const u16* __restrict__ Bp, const float* __restrict__ bnp,
    float* __restrict__ outF, u16* __restrict__ oHi, u16* __restrict__ oLo,
    int m0, int n0, int M, int OC, int C, int H, int W, int OH, int OW) {
    const int Ktot = KHW * C;
    const int nKb = Ktot >> 6;   // 64-wide K blocks
    const int nK32 = Ktot >> 5;  // 32-wide (Bp granularity)
    const int tid = threadIdx.x;
    const int OHW = OH * OW;

    // A staging: 128 rows x 64 k x 2B = 16KB per dtype. 1024 chunks of 16B.
    // chunk q of row ml holds global chunk q ^ (ml&7)  (bank spread).
    int abase[4];
    {
        int q = tid & 7;
        int mlb = tid >> 3;
#pragma unroll
        for (int s = 0; s < 4; ++s) {
            int ml = s * 32 + mlb;
            int qs = q ^ (ml & 7);
            int m = m0 + ml;
            if (m >= M) m = M - 1;
            int b = m / OHW;
            int r = m - b * OHW;
            int y = r / OW;
            int x = r - y * OW;
            abase[s] = ((b * H + y) * W + x) * C + qs * 8;
        }
    }
    const int lds0 = tid * 8;  // element offset; slot s adds 2048

    f32x4 acc[4][4];
#pragma unroll
    for (int i = 0; i < 4; ++i)
#pragma unroll
        for (int j = 0; j < 4; ++j) acc[i][j] = (f32x4)0.f;

    const int lane = tid & 63;
    const int row = lane & 15;
    const int quad = lane >> 4;
    const int wv = tid >> 6;
    const int wm = (wv & 1) * 64;
    const int wn = (wv >> 1) * 64;
    const int octb = (n0 + wn) >> 4;
    const u16* bptr = Bp + (size_t)octb * nK32 * 1024 + lane * 8;
    const int r7 = row & 7;

    for (int kb = 0; kb < nKb; ++kb) {
        int koff;
        if (KHW == 9) {
            // C == 256: 4 sub-blocks of 64 channels per (ky,kx)
            int pos = kb >> 2;
            int cin0 = (kb & 3) << 6;
            int ky = pos / 3;
            int kx = pos - ky * 3;
            koff = (ky * W + kx) * C + cin0;
        } else {
            koff = kb << 6;
        }
#pragma unroll
        for (int s = 0; s < 4; ++s)
            async_copy16(&sA[lds0 + s * 2048], Ahi + abase[s] + koff);
#pragma unroll
        for (int s = 0; s < 4; ++s)
            async_copy16(&sA[8192 + lds0 + s * 2048], Alo + abase[s] + koff);

        // B fragments straight from global (coalesced 16B/lane, L2-hot).
        const u16* bk = bptr + (size_t)kb * 2048;
        bf16x8 bh[2][4], bl[2][4];
#pragma unroll
        for (int ks = 0; ks < 2; ++ks)
#pragma unroll
            for (int j = 0; j < 4; ++j) {
                const u16* p = bk + (size_t)j * nK32 * 1024 + ks * 1024;
                bh[ks][j] = *(const bf16x8*)p;
                bl[ks][j] = *(const bf16x8*)(p + 512);
            }
        __syncthreads();

#pragma unroll
        for (int ks = 0; ks < 2; ++ks) {
            bf16x8 ah[4], al[4];
#pragma unroll
            for (int i = 0; i < 4; ++i) {
                int g = wm + i * 16 + row;
                int off = g * 64 + ((((ks << 2) | quad) ^ r7) << 3);
                ah[i] = *(const bf16x8*)&sA[off];
                al[i] = *(const bf16x8*)&sA[8192 + off];
            }
#pragma unroll
            for (int i = 0; i < 4; ++i)
#pragma unroll
                for (int j = 0; j < 4; ++j) {
                    acc[i][j] = __builtin_amdgcn_mfma_f32_16x16x32_bf16(
                        ah[i], bh[ks][j], acc[i][j], 0, 0, 0);
                    acc[i][j] = __builtin_amdgcn_mfma_f32_16x16x32_bf16(
                        al[i], bh[ks][j], acc[i][j], 0, 0, 0);
                    acc[i][j] = __builtin_amdgcn_mfma_f32_16x16x32_bf16(
                        ah[i], bl[ks][j], acc[i][j], 0, 0, 0);
                }
        }
        __syncthreads();
    }

    // Epilogue. C/D layout: col(n) = lane&15, row(m) = quad*4 + reg.
#pragma unroll
    for (int j = 0; j < 4; ++j) {
        int oc = n0 + wn + j * 16 + row;
        bool ocv = oc < OC;
        float scale = 1.f, shift = 0.f;
        if (ocv) {
            if (EPI <= 2) {
                float g = bnp[oc];
                float bb = bnp[OC + oc];
                float mm = bnp[2 * OC + oc];
                float vv = bnp[3 * OC + oc];
                float inv = g * rsqrtf(vv + EPSBN);
                scale = inv;
                shift = bb - mm * inv;
            } else {
                shift = bnp[oc];  // bias
            }
        }
#pragma unroll
        for (int i = 0; i < 4; ++i) {
#pragma unroll
            for (int r = 0; r < 4; ++r) {
                int m = m0 + wm + i * 16 + quad * 4 + r;
                if (m < M && ocv) {
                    float v = acc[i][j][r] * scale + shift;
                    if (EPI == 0 || EPI == 2) v = fmaxf(v, 0.f);
                    if (EPI == 0) {
                        outF[(size_t)m * OC + oc] = v;
                    } else if (EPI == 3) {
                        int b = m / OHW;
                        int rr = m - b * OHW;
                        outF[((size_t)b * OC + oc) * OHW + rr] = v;
                    } else {
                        u16 h, l;
                        split_bf16(v, h, l);
                        oHi[(size_t)m * OC + oc] = h;
                        oLo[(size_t)m * OC + oc] = l;
                    }
                }
            }
        }
    }
}

// Fused conv3x3 for search (x-blocks [0,421)) and kernel (x-blocks [421,434)).
__global__ __launch_bounds__(256, 2) void conv33_fused(
    const u16* sAhi_g, const u16* sAlo_g, const u16* bpS, const float* bns,
    float* sOut, const u16* kAhi_g, const u16* kAlo_g, const u16* bpK,
    const float* bnk, float* kOut) {
    __shared__ u16 sA[16384];
    bool sec = blockIdx.x >= 421;
    const u16* Ahi = sec ? kAhi_g : sAhi_g;
    const u16* Alo = sec ? kAlo_g : sAlo_g;
    const u16* Bp = sec ? bpK : bpS;
    const float* bnp = sec ? bnk : bns;
    float* outF = sec ? kOut : sOut;
    int M = sec ? 1600 : 53824;
    int H = sec ? 7 : 31;
    int OHs = sec ? 5 : 29;
    int m0 = (blockIdx.x - (sec ? 421 : 0)) * 128;
    int n0 = blockIdx.y * 128;
    gemm_body<9, 0>(sA, Ahi, Alo, Bp, bnp, outF, nullptr, nullptr, m0, n0, M,
                    256, 256, H, H, OHs, OHs);
}

template <int EPI>
__global__ __launch_bounds__(256, 2) void gemm_1x1(
    const u16* __restrict__ Ahi, const u16* __restrict__ Alo,
    const u16* __restrict__ Bp, const float* __restrict__ bnp,
    float* __restrict__ outF, u16* __restrict__ oHi, u16* __restrict__ oLo,
    int M, int OC, int C) {
    __shared__ u16 sA[16384];
    gemm_body<1, EPI>(sA, Ahi, Alo, Bp, bnp, outF, oHi, oLo,
                      blockIdx.x * 128, blockIdx.y * 128, M, OC, C, 25, 25,
                      25, 25);
}

// ---------------------------------------------------------------------------
// Multi-scale depthwise xcorr, NHWC fp32 in, bf16-pair NHWC out.
// Sliding 5x5 window: 5 fresh loads per x instead of 25.
// ---------------------------------------------------------------------------
__global__ __launch_bounds__(256) void xcorr_nhwc(
    const float* __restrict__ sf, const float* __restrict__ kf,
    u16* __restrict__ fhi, u16* __restrict__ flo) {
    int by = blockIdx.x;  // b*25 + y
    int b = by / 25;
    int y = by - b * 25;
    int c = threadIdx.x;  // 0..255
    float kv[25];
#pragma unroll
    for (int p = 0; p < 25; ++p) kv[p] = kf[(size_t)(b * 25 + p) * 256 + c];
    const float* srow = sf + (size_t)(b * 29 + y) * 29 * 256 + c;
    float sv[25];
#pragma unroll
    for (int d = 0; d < 5; ++d)
#pragma unroll
        for (int e = 0; e < 5; ++e)
            sv[d * 5 + e] = srow[(size_t)(d * 29 + e) * 256];
    for (int x = 0;; ++x) {
        float a0 = 0.f, a1 = 0.f, a2;
#pragma unroll
        for (int p = 0; p < 25; ++p) a0 = fmaf(sv[p], kv[p], a0);
#pragma unroll
        for (int d = 1; d < 4; ++d)
#pragma unroll
            for (int e = 1; e < 4; ++e)
                a1 = fmaf(sv[d * 5 + e], kv[d * 5 + e], a1);
        a2 = sv[12] * kv[12];
        size_t o = ((size_t)by * 25 + x) * 768 + c;
        u16 h, l;
        split_bf16(a0, h, l);
        fhi[o] = h;
        flo[o] = l;
        split_bf16(a1, h, l);
        fhi[o + 256] = h;
        flo[o + 256] = l;
        split_bf16(a2, h, l);
        fhi[o + 512] = h;
        flo[o + 512] = l;
        if (x == 24) break;
#pragma unroll
        for (int d = 0; d < 5; ++d) {
#pragma unroll
            for (int e = 0; e < 4; ++e) sv[d * 5 + e] = sv[d * 5 + e + 1];
            sv[d * 5 + 4] = srow[(size_t)(d * 29 + x + 5) * 256];
        }
    }
}

// ---------------------------------------------------------------------------
extern "C" void kernel_launch(void* const* d_in, const int* in_sizes, int n_in,
                              void* d_out, int out_size, void* d_ws,
                              size_t ws_size, hipStream_t stream) {
    const float* kernel_in = (const float*)d_in[0];  // (64,256,7,7)
    const float* search_in = (const float*)d_in[1];  // (64,256,31,31)
    const float* wk = (const float*)d_in[2];         // (256,256,3,3)
    const float* bnk = (const float*)d_in[3];
    const float* ws = (const float*)d_in[4];
    const float* bns = (const float*)d_in[5];
    const float* wd = (const float*)d_in[6];  // (256,768)
    const float* bnd = (const float*)d_in[7];
    const float* wh1 = (const float*)d_in[8];  // (256,256)
    const float* bnh = (const float*)d_in[9];
    const float* wh2 = (const float*)d_in[10];  // (10,256)
    const float* bh2 = (const float*)d_in[11];  // (10,)
    float* out = (float*)d_out;                 // (64,10,25,25) NCHW

    char* base = (char*)d_ws;
    size_t off = 0;
    auto alloc = [&](size_t bytes) {
        off = (off + 511) & ~(size_t)511;
        void* p = base + off;
        off += bytes;
        return p;
    };

    // Persistent region
    u16* bpd = (u16*)alloc((size_t)16 * 24 * 1024 * 2);  // wd frags
    u16* bp1 = (u16*)alloc((size_t)16 * 8 * 1024 * 2);   // wh1 frags
    u16* bp2 = (u16*)alloc((size_t)8 * 8 * 1024 * 2);    // wh2 frags (padded)
    size_t Pf = (off + 511) & ~(size_t)511;  // f2 aliases here later
    float* kfeat = (float*)alloc((size_t)1600 * 256 * 4);
    float* sfeat = (float*)alloc((size_t)53824 * 256 * 4);
    size_t P1 = (off + 511) & ~(size_t)511;  // feat/hbuf alias here
    // Transients (dead after conv33_fused)
    u16* bpk = (u16*)alloc((size_t)16 * 72 * 1024 * 2);
    u16* bps = (u16*)alloc((size_t)16 * 72 * 1024 * 2);
    u16* ka_hi = (u16*)alloc((size_t)64 * 49 * 256 * 2);
    u16* ka_lo = (u16*)alloc((size_t)64 * 49 * 256 * 2);
    u16* sa_hi = (u16*)alloc((size_t)64 * 961 * 256 * 2);
    u16* sa_lo = (u16*)alloc((size_t)64 * 961 * 256 * 2);
    // Aliases
    u16* feat_hi = (u16*)(base + P1);  // 64*625*768
    u16* feat_lo = feat_hi + (size_t)64 * 625 * 768;
    u16* f2_hi = (u16*)(base + Pf);  // 40000*256
    u16* f2_lo = f2_hi + (size_t)40000 * 256;
    u16* h_hi = (u16*)(base + P1);  // 40000*256
    u16* h_lo = h_hi + (size_t)40000 * 256;

    // 1) activation transpose+split (search z=0..15, kernel z=16)
    trans_split_all<<<dim3(64, 4, 17), 256, 0, stream>>>(
        search_in, sa_hi, sa_lo, kernel_in, ka_hi, ka_lo);
    // 2) all weight fragment packs
    prep_frags<<<dim3(5760), 256, 0, stream>>>(wk, ws, wd, wh1, wh2, bpk, bps,
                                               bpd, bp1, bp2);
    // 3) fused conv3x3 (search + kernel branches)
    conv33_fused<<<dim3(434, 2), 256, 0, stream>>>(
        sa_hi, sa_lo, bps, bns, sfeat, ka_hi, ka_lo, bpk, bnk, kfeat);
    // 4) xcorr -> feat bf16 pair NHWC [40000][768]
    xcorr_nhwc<<<dim3(1600), 256, 0, stream>>>(sfeat, kfeat, feat_hi, feat_lo);
    // 5) wd: 1x1, K=768, BN -> f2 pair
    gemm_1x1<1><<<dim3(313, 2), 256, 0, stream>>>(
        feat_hi, feat_lo, bpd, bnd, nullptr, f2_hi, f2_lo, 40000, 256, 768);
    // 6) wh1: 1x1, K=256, BN+ReLU -> h pair
    gemm_1x1<2><<<dim3(313, 2), 256, 0, stream>>>(
        f2_hi, f2_lo, bp1, bnh, nullptr, h_hi, h_lo, 40000, 256, 256);
    // 7) wh2: 1x1, K=256, +bias -> out f32 NCHW
    gemm_1x1<3><<<dim3(313, 1), 256, 0, stream>>>(
        h_hi, h_lo, bp2, bh2, out, nullptr, nullptr, 40000, 10, 256);
}

// Round 5
// 401.375 us; speedup vs baseline: 6.5563x; 1.2672x over previous
//
#include <hip/hip_runtime.h>
#include <hip/hip_bf16.h>
#include <cstdint>
#include <cstddef>

#define EPSBN 1e-5f

typedef unsigned short u16;
typedef unsigned int u32;
typedef _Float16 f16;
typedef _Float16 f16x8 __attribute__((ext_vector_type(8)));
typedef float f32x4 __attribute__((ext_vector_type(4)));

// async global->LDS, 16B per lane
__device__ __forceinline__ void async_copy16(void* lds, const void* g) {
    __builtin_amdgcn_global_load_lds(
        (const __attribute__((address_space(1))) u32*)g,
        (__attribute__((address_space(3))) u32*)lds, 16, 0, 0);
}

// ---------------------------------------------------------------------------
// NCHW fp32 -> NHWC f16 for BOTH activations (z=16 -> kernel input).
// ---------------------------------------------------------------------------
__global__ __launch_bounds__(256) void trans_f16_all(
    const float* __restrict__ sin, f16* __restrict__ sa,
    const float* __restrict__ kin, f16* __restrict__ ka) {
    __shared__ float tile[64][65];
    int b = blockIdx.x;
    int c0 = blockIdx.y * 64;
    bool isk = (blockIdx.z == 16);
    const float* in = isk ? kin : sin;
    f16* outp = isk ? ka : sa;
    int HW = isk ? 49 : 961;
    int h0 = isk ? 0 : blockIdx.z * 64;
    int cl = threadIdx.x >> 6;  // 0..3
    int hl = threadIdx.x & 63;
    for (int r = cl; r < 64; r += 4) {
        int hw = h0 + hl;
        tile[r][hl] =
            (hw < HW) ? in[(size_t)(b * 256 + c0 + r) * HW + hw] : 0.f;
    }
    __syncthreads();
    int c = threadIdx.x & 63;
    for (int r = cl; r < 64; r += 4) {
        int hw = h0 + r;
        if (hw < HW)
            outp[((size_t)b * HW + hw) * 256 + c0 + c] = (f16)tile[c][r];
    }
}

// ---------------------------------------------------------------------------
// Pack weights into MFMA B-fragment order, f16 hi + (residual*2048) lo:
//   Bp[oct][k32][hi 512 | lo 512], entry (lane,j):
//   oc = oct*16 + (lane&15), k = k32*32 + (lane>>4)*8 + j
// K-order for 3x3 convs is (pos, cin): k = pos*256 + cin (matches A im2col).
// blocks: [0,2304) wk | [2304,4608) ws | [4608,5376) wd | [5376,5632) wh1 |
//         [5632,5760) wh2 (OC padded to 128, zeros beyond oc 10)
// ---------------------------------------------------------------------------
__global__ __launch_bounds__(256) void prep_frags(
    const float* __restrict__ wk, const float* __restrict__ ws,
    const float* __restrict__ wd, const float* __restrict__ wh1,
    const float* __restrict__ wh2, f16* __restrict__ bpk,
    f16* __restrict__ bps, f16* __restrict__ bpd, f16* __restrict__ bp1,
    f16* __restrict__ bp2) {
    int blk = blockIdx.x, tid = threadIdx.x;
    const float* W;
    f16* Bp;
    int nK32, OCr, K, i;
    bool conv = false;
    if (blk < 2304) {
        W = wk; Bp = bpk; nK32 = 72; OCr = 256; K = 2304; conv = true;
        i = blk * 256 + tid;
    } else if (blk < 4608) {
        W = ws; Bp = bps; nK32 = 72; OCr = 256; K = 2304; conv = true;
        i = (blk - 2304) * 256 + tid;
    } else if (blk < 5376) {
        W = wd; Bp = bpd; nK32 = 24; OCr = 256; K = 768;
        i = (blk - 4608) * 256 + tid;
    } else if (blk < 5632) {
        W = wh1; Bp = bp1; nK32 = 8; OCr = 256; K = 256;
        i = (blk - 5376) * 256 + tid;
    } else {
        W = wh2; Bp = bp2; nK32 = 8; OCr = 10; K = 256;
        i = (blk - 5632) * 256 + tid;
    }
    int per = nK32 * 512;
    int oct = i / per;
    int r = i - oct * per;
    int k32 = r >> 9;
    int lr = r & 511;
    int l = lr >> 3, j = lr & 7;
    int oc = oct * 16 + (l & 15);
    int k = k32 * 32 + ((l >> 4) << 3) + j;
    float v = 0.f;
    if (oc < OCr)
        v = conv ? W[(size_t)(oc * 256 + (k & 255)) * 9 + (k >> 8)]
                 : W[(size_t)oc * K + k];
    f16 h = (f16)v;
    f16 lo = (f16)((v - (float)h) * 2048.0f);
    size_t o = (size_t)(oct * nK32 + k32) * 1024 + lr;
    Bp[o] = h;
    Bp[o + 512] = lo;
}

// ---------------------------------------------------------------------------
// f16 MFMA GEMM: A (single f16) staged in LDS (BK=64, XOR-swizzled),
// B fragments (f16 hi + scaled lo) straight from global (prepacked, L2-hot).
// BM=BN=128, 256 thr, 4 waves (2m x 2n), each 64x64 via 4x4 16x16x32 MFMA.
// 2 MFMA per product: A*Bh -> acc, A*Bl -> accl; D = acc + accl/2048.
// EPI: 0 BN+ReLU->f32 NHWC; 1 BN->f16 NHWC; 2 BN+ReLU->f16 NHWC;
//      3 +bias->f32 NCHW.
// ---------------------------------------------------------------------------
template <int KHW, int EPI>
__device__ __forceinline__ void gemm_body(
    f16* sA, const f16* __restrict__ A, const f16* __restrict__ Bp,
    const float* __restrict__ bnp, float* __restrict__ outF,
    f16* __restrict__ oF, int m0, int n0, int M, int OC, int C, int H, int W,
    int OH, int OW) {
    const int Ktot = KHW * C;
    const int nKb = Ktot >> 6;   // 64-wide K blocks
    const int nK32 = Ktot >> 5;  // 32-wide (Bp granularity)
    const int tid = threadIdx.x;
    const int OHW = OH * OW;

    // A staging: 128 rows x 64 k x 2B = 16KB. 1024 chunks of 16B.
    // chunk q of row ml holds global chunk q ^ (ml&7) (bank spread).
    int abase[4];
    {
        int q = tid & 7;
        int mlb = tid >> 3;
#pragma unroll
        for (int s = 0; s < 4; ++s) {
            int ml = s * 32 + mlb;
            int qs = q ^ (ml & 7);
            int m = m0 + ml;
            if (m >= M) m = M - 1;
            int b = m / OHW;
            int r = m - b * OHW;
            int y = r / OW;
            int x = r - y * OW;
            abase[s] = ((b * H + y) * W + x) * C + qs * 8;
        }
    }
    const int lds0 = tid * 8;  // element offset; slot s adds 2048

    f32x4 acc[4][4], accl[4][4];
#pragma unroll
    for (int i = 0; i < 4; ++i)
#pragma unroll
        for (int j = 0; j < 4; ++j) {
            acc[i][j] = (f32x4)0.f;
            accl[i][j] = (f32x4)0.f;
        }

    const int lane = tid & 63;
    const int row = lane & 15;
    const int quad = lane >> 4;
    const int wv = tid >> 6;
    const int wm = (wv & 1) * 64;
    const int wn = (wv >> 1) * 64;
    const int octb = (n0 + wn) >> 4;
    const f16* bptr = Bp + (size_t)octb * nK32 * 1024 + lane * 8;
    const int r7 = row & 7;

    for (int kb = 0; kb < nKb; ++kb) {
        int koff;
        if (KHW == 9) {
            // C == 256: 4 sub-blocks of 64 channels per (ky,kx)
            int pos = kb >> 2;
            int cin0 = (kb & 3) << 6;
            int ky = pos / 3;
            int kx = pos - ky * 3;
            koff = (ky * W + kx) * C + cin0;
        } else {
            koff = kb << 6;
        }
#pragma unroll
        for (int s = 0; s < 4; ++s)
            async_copy16(&sA[lds0 + s * 2048], A + abase[s] + koff);

        // B fragments straight from global (coalesced 16B/lane, L2-hot).
        const f16* bk = bptr + (size_t)kb * 2048;
        f16x8 bh[2][4], bl[2][4];
#pragma unroll
        for (int ks = 0; ks < 2; ++ks)
#pragma unroll
            for (int j = 0; j < 4; ++j) {
                const f16* p = bk + (size_t)j * nK32 * 1024 + ks * 1024;
                bh[ks][j] = *(const f16x8*)p;
                bl[ks][j] = *(const f16x8*)(p + 512);
            }
        __syncthreads();

#pragma unroll
        for (int ks = 0; ks < 2; ++ks) {
            f16x8 ah[4];
#pragma unroll
            for (int i = 0; i < 4; ++i) {
                int g = wm + i * 16 + row;
                int off = g * 64 + ((((ks << 2) | quad) ^ r7) << 3);
                ah[i] = *(const f16x8*)&sA[off];
            }
#pragma unroll
            for (int i = 0; i < 4; ++i)
#pragma unroll
                for (int j = 0; j < 4; ++j) {
                    acc[i][j] = __builtin_amdgcn_mfma_f32_16x16x32_f16(
                        ah[i], bh[ks][j], acc[i][j], 0, 0, 0);
                    accl[i][j] = __builtin_amdgcn_mfma_f32_16x16x32_f16(
                        ah[i], bl[ks][j], accl[i][j], 0, 0, 0);
                }
        }
        __syncthreads();
    }

    // Epilogue. C/D layout: col(n) = lane&15, row(m) = quad*4 + reg.
#pragma unroll
    for (int j = 0; j < 4; ++j) {
        int oc = n0 + wn + j * 16 + row;
        bool ocv = oc < OC;
        float scale = 1.f, shift = 0.f;
        if (ocv) {
            if (EPI <= 2) {
                float g = bnp[oc];
                float bb = bnp[OC + oc];
                float mm = bnp[2 * OC + oc];
                float vv = bnp[3 * OC + oc];
                float inv = g * rsqrtf(vv + EPSBN);
                scale = inv;
                shift = bb - mm * inv;
            } else {
                shift = bnp[oc];  // bias
            }
        }
#pragma unroll
        for (int i = 0; i < 4; ++i) {
#pragma unroll
            for (int r = 0; r < 4; ++r) {
                int m = m0 + wm + i * 16 + quad * 4 + r;
                if (m < M && ocv) {
                    float v =
                        acc[i][j][r] + accl[i][j][r] * 4.8828125e-4f;
                    v = v * scale + shift;
                    if (EPI == 0 || EPI == 2) v = fmaxf(v, 0.f);
                    if (EPI == 0) {
                        outF[(size_t)m * OC + oc] = v;
                    } else if (EPI == 3) {
                        int b = m / OHW;
                        int rr = m - b * OHW;
                        outF[((size_t)b * OC + oc) * OHW + rr] = v;
                    } else {
                        oF[(size_t)m * OC + oc] = (f16)v;
                    }
                }
            }
        }
    }
}

// Fused conv3x3 for search (x-blocks [0,421)) and kernel (x-blocks [421,434)).
__global__ __launch_bounds__(256, 2) void conv33_fused(
    const f16* sA_g, const f16* bpS, const float* bns, float* sOut,
    const f16* kA_g, const f16* bpK, const float* bnk, float* kOut) {
    __shared__ f16 sA[8192];
    bool sec = blockIdx.x >= 421;
    const f16* A = sec ? kA_g : sA_g;
    const f16* Bp = sec ? bpK : bpS;
    const float* bnp = sec ? bnk : bns;
    float* outF = sec ? kOut : sOut;
    int M = sec ? 1600 : 53824;
    int H = sec ? 7 : 31;
    int OHs = sec ? 5 : 29;
    int m0 = (blockIdx.x - (sec ? 421 : 0)) * 128;
    int n0 = blockIdx.y * 128;
    gemm_body<9, 0>(sA, A, Bp, bnp, outF, nullptr, m0, n0, M, 256, 256, H, H,
                    OHs, OHs);
}

template <int EPI>
__global__ __launch_bounds__(256, 2) void gemm_1x1(
    const f16* __restrict__ A, const f16* __restrict__ Bp,
    const float* __restrict__ bnp, float* __restrict__ outF,
    f16* __restrict__ oF, int M, int OC, int C) {
    __shared__ f16 sA[8192];
    gemm_body<1, EPI>(sA, A, Bp, bnp, outF, oF, blockIdx.x * 128,
                      blockIdx.y * 128, M, OC, C, 25, 25, 25, 25);
}

// ---------------------------------------------------------------------------
// Multi-scale depthwise xcorr, NHWC fp32 in, f16 NHWC out.
// Sliding 5x5 window: 5 fresh loads per x instead of 25.
// ---------------------------------------------------------------------------
__global__ __launch_bounds__(256) void xcorr_nhwc(
    const float* __restrict__ sf, const float* __restrict__ kf,
    f16* __restrict__ feat) {
    int by = blockIdx.x;  // b*25 + y
    int b = by / 25;
    int y = by - b * 25;
    int c = threadIdx.x;  // 0..255
    float kv[25];
#pragma unroll
    for (int p = 0; p < 25; ++p) kv[p] = kf[(size_t)(b * 25 + p) * 256 + c];
    const float* srow = sf + (size_t)(b * 29 + y) * 29 * 256 + c;
    float sv[25];
#pragma unroll
    for (int d = 0; d < 5; ++d)
#pragma unroll
        for (int e = 0; e < 5; ++e)
            sv[d * 5 + e] = srow[(size_t)(d * 29 + e) * 256];
    for (int x = 0;; ++x) {
        float a0 = 0.f, a1 = 0.f, a2;
#pragma unroll
        for (int p = 0; p < 25; ++p) a0 = fmaf(sv[p], kv[p], a0);
#pragma unroll
        for (int d = 1; d < 4; ++d)
#pragma unroll
            for (int e = 1; e < 4; ++e)
                a1 = fmaf(sv[d * 5 + e], kv[d * 5 + e], a1);
        a2 = sv[12] * kv[12];
        size_t o = ((size_t)by * 25 + x) * 768 + c;
        feat[o] = (f16)a0;
        feat[o + 256] = (f16)a1;
        feat[o + 512] = (f16)a2;
        if (x == 24) break;
#pragma unroll
        for (int d = 0; d < 5; ++d) {
#pragma unroll
            for (int e = 0; e < 4; ++e) sv[d * 5 + e] = sv[d * 5 + e + 1];
            sv[d * 5 + 4] = srow[(size_t)(d * 29 + x + 5) * 256];
        }
    }
}

// ---------------------------------------------------------------------------
extern "C" void kernel_launch(void* const* d_in, const int* in_sizes, int n_in,
                              void* d_out, int out_size, void* d_ws,
                              size_t ws_size, hipStream_t stream) {
    const float* kernel_in = (const float*)d_in[0];  // (64,256,7,7)
    const float* search_in = (const float*)d_in[1];  // (64,256,31,31)
    const float* wk = (const float*)d_in[2];         // (256,256,3,3)
    const float* bnk = (const float*)d_in[3];
    const float* ws = (const float*)d_in[4];
    const float* bns = (const float*)d_in[5];
    const float* wd = (const float*)d_in[6];  // (256,768)
    const float* bnd = (const float*)d_in[7];
    const float* wh1 = (const float*)d_in[8];  // (256,256)
    const float* bnh = (const float*)d_in[9];
    const float* wh2 = (const float*)d_in[10];  // (10,256)
    const float* bh2 = (const float*)d_in[11];  // (10,)
    float* out = (float*)d_out;                 // (64,10,25,25) NCHW

    char* base = (char*)d_ws;
    size_t off = 0;
    auto alloc = [&](size_t bytes) {
        off = (off + 511) & ~(size_t)511;
        void* p = base + off;
        off += bytes;
        return p;
    };

    // Persistent region
    f16* bpd = (f16*)alloc((size_t)16 * 24 * 1024 * 2);  // wd frags
    f16* bp1 = (f16*)alloc((size_t)16 * 8 * 1024 * 2);   // wh1 frags
    f16* bp2 = (f16*)alloc((size_t)8 * 8 * 1024 * 2);    // wh2 frags (padded)
    size_t Pf = (off + 511) & ~(size_t)511;  // f2 aliases here later
    float* kfeat = (float*)alloc((size_t)1600 * 256 * 4);
    float* sfeat = (float*)alloc((size_t)53824 * 256 * 4);
    size_t P1 = (off + 511) & ~(size_t)511;  // feat/hbuf alias here
    // Transients (dead after conv33_fused)
    f16* bpk = (f16*)alloc((size_t)16 * 72 * 1024 * 2);
    f16* bps = (f16*)alloc((size_t)16 * 72 * 1024 * 2);
    f16* ka = (f16*)alloc((size_t)64 * 49 * 256 * 2);
    f16* sa = (f16*)alloc((size_t)64 * 961 * 256 * 2);
    // Aliases
    f16* feat = (f16*)(base + P1);  // 40000*768 (dead transients region)
    f16* f2 = (f16*)(base + Pf);    // 40000*256 (kfeat/sfeat dead)
    f16* hb = (f16*)(base + P1);    // 40000*256 (feat dead)

    // 1) activation transpose -> f16 NHWC (search z=0..15, kernel z=16)
    trans_f16_all<<<dim3(64, 4, 17), 256, 0, stream>>>(search_in, sa,
                                                       kernel_in, ka);
    // 2) all weight fragment packs (f16 hi + scaled lo)
    prep_frags<<<dim3(5760), 256, 0, stream>>>(wk, ws, wd, wh1, wh2, bpk, bps,
                                               bpd, bp1, bp2);
    // 3) fused conv3x3 (search + kernel branches) -> f32 NHWC
    conv33_fused<<<dim3(434, 2), 256, 0, stream>>>(sa, bps, bns, sfeat, ka,
                                                   bpk, bnk, kfeat);
    // 4) xcorr -> feat f16 NHWC [40000][768]
    xcorr_nhwc<<<dim3(1600), 256, 0, stream>>>(sfeat, kfeat, feat);
    // 5) wd: 1x1, K=768, BN -> f2 f16
    gemm_1x1<1><<<dim3(313, 2), 256, 0, stream>>>(feat, bpd, bnd, nullptr, f2,
                                                  40000, 256, 768);
    // 6) wh1: 1x1, K=256, BN+ReLU -> h f16
    gemm_1x1<2><<<dim3(313, 2), 256, 0, stream>>>(f2, bp1, bnh, nullptr, hb,
                                                  40000, 256, 256);
    // 7) wh2: 1x1, K=256, +bias -> out f32 NCHW
    gemm_1x1<3><<<dim3(313, 1), 256, 0, stream>>>(hb, bp2, bh2, out, nullptr,
                                                  40000, 10, 256);
}

// Round 7
// 332.316 us; speedup vs baseline: 7.9188x; 1.2078x over previous
//
#include <hip/hip_runtime.h>
#include <hip/hip_bf16.h>
#include <cstdint>
#include <cstddef>

#define EPSBN 1e-5f

typedef unsigned short u16;
typedef unsigned int u32;
typedef _Float16 f16;
typedef _Float16 f16x8 __attribute__((ext_vector_type(8)));
typedef float f32x4 __attribute__((ext_vector_type(4)));

// async global->LDS, 16B per lane
__device__ __forceinline__ void async_copy16(void* lds, const void* g) {
    __builtin_amdgcn_global_load_lds(
        (const __attribute__((address_space(1))) u32*)g,
        (__attribute__((address_space(3))) u32*)lds, 16, 0, 0);
}

// ---------------------------------------------------------------------------
// One prep kernel:
//  blocks [0,4352): NCHW f32 -> NHWC f16 transpose (search + kernel acts)
//  blocks [4352,...): weight fragment packing, f16 only:
//    Bp[oct][k32][lane][j] = W[oct*16+(lane&15)][k32*32+(lane>>4)*8+j]
//    3x3 convs use k = pos*256+cin (matches A im2col order).
//    ranges (blocks): wk 2304 | ws 2304 | wd 768 | wh1 256 | wh2 128
//    (wh2 OC padded to 128, zeros beyond oc 10)
// ---------------------------------------------------------------------------
__global__ __launch_bounds__(256) void prep_all(
    const float* __restrict__ sin, f16* __restrict__ sa,
    const float* __restrict__ kin, f16* __restrict__ ka,
    const float* __restrict__ wk, const float* __restrict__ ws,
    const float* __restrict__ wd, const float* __restrict__ wh1,
    const float* __restrict__ wh2, f16* __restrict__ bpk,
    f16* __restrict__ bps, f16* __restrict__ bpd, f16* __restrict__ bp1,
    f16* __restrict__ bp2) {
    __shared__ float tile[64][65];
    int t = blockIdx.x;
    int tid = threadIdx.x;
    if (t < 4352) {  // 64 b x 4 ctiles x 17 z
        int b = t / 68;
        int rem = t - b * 68;
        int c0 = (rem / 17) * 64;
        int z = rem % 17;
        bool isk = (z == 16);
        const float* in = isk ? kin : sin;
        f16* op = isk ? ka : sa;
        int HW = isk ? 49 : 961;
        int h0 = isk ? 0 : z * 64;
        int cl = tid >> 6;
        int hl = tid & 63;
        for (int r = cl; r < 64; r += 4) {
            int hw = h0 + hl;
            tile[r][hl] =
                (hw < HW) ? in[(size_t)(b * 256 + c0 + r) * HW + hw] : 0.f;
        }
        __syncthreads();
        int c = tid & 63;
        for (int r = cl; r < 64; r += 4) {
            int hw = h0 + r;
            if (hw < HW)
                op[((size_t)b * HW + hw) * 256 + c0 + c] = (f16)tile[c][r];
        }
        return;
    }
    int blk = t - 4352;
    const float* W;
    f16* Bp;
    int nK32, OCr, K, i;
    bool conv = false;
    if (blk < 2304) {
        W = wk; Bp = bpk; nK32 = 72; OCr = 256; K = 2304; conv = true;
        i = blk * 256 + tid;
    } else if (blk < 4608) {
        W = ws; Bp = bps; nK32 = 72; OCr = 256; K = 2304; conv = true;
        i = (blk - 2304) * 256 + tid;
    } else if (blk < 5376) {  // wd: 16 octs * 24 k32 * 512 = 768 blocks
        W = wd; Bp = bpd; nK32 = 24; OCr = 256; K = 768;
        i = (blk - 4608) * 256 + tid;
    } else if (blk < 5632) {
        W = wh1; Bp = bp1; nK32 = 8; OCr = 256; K = 256;
        i = (blk - 5376) * 256 + tid;
    } else {
        W = wh2; Bp = bp2; nK32 = 8; OCr = 10; K = 256;
        i = (blk - 5632) * 256 + tid;
    }
    int per = nK32 * 512;
    int oct = i / per;
    int r = i - oct * per;
    int k32 = r >> 9;
    int lr = r & 511;
    int l = lr >> 3, j = lr & 7;
    int oc = oct * 16 + (l & 15);
    int k = k32 * 32 + ((l >> 4) << 3) + j;
    float v = 0.f;
    if (oc < OCr)
        v = conv ? W[(size_t)(oc * 256 + (k & 255)) * 9 + (k >> 8)]
                 : W[(size_t)oc * K + k];
    Bp[(size_t)(oct * nK32 + k32) * 512 + lr] = (f16)v;
}

// ---------------------------------------------------------------------------
// f16 MFMA GEMM: A staged in LDS, BK=128 (32KB, XOR-swizzled 16-chunk rows),
// B fragments straight from global (prepacked fragment order, L2-hot).
// BM=BN=128, 256 thr, 4 waves (2m x 2n), each 64x64 via 4x4 16x16x32 MFMA.
// EPI: 1 BN->f16 NHWC; 2 BN+ReLU->f16 NHWC; 3 +bias->f32 NCHW.
// ---------------------------------------------------------------------------
template <int KHW, int EPI>
__device__ __forceinline__ void gemm_body(
    f16* sA, const f16* __restrict__ A, const f16* __restrict__ Bp,
    const float* __restrict__ bnp, float* __restrict__ outF,
    f16* __restrict__ oF, int m0, int n0, int M, int OC, int C, int H, int W,
    int OH, int OW) {
    const int Ktot = KHW * C;
    const int nKb = Ktot >> 7;   // 128-wide K windows
    const int nK32 = Ktot >> 5;  // Bp granularity
    const int tid = threadIdx.x;
    const int OHW = OH * OW;

    // A staging: 128 rows x 128 k x 2B = 32KB. 2048 chunks of 16B.
    // LDS[ml][q] holds global chunk q ^ (ml&15)  (read-side bank spread).
    int abase[8];
#pragma unroll
    for (int s = 0; s < 8; ++s) {
        int idx = tid + s * 256;
        int ml = idx >> 4;
        int qs = (idx & 15) ^ (ml & 15);
        int m = m0 + ml;
        if (m >= M) m = M - 1;
        int b = m / OHW;
        int r = m - b * OHW;
        int y = r / OW;
        int x = r - y * OW;
        abase[s] = ((b * H + y) * W + x) * C + qs * 8;
    }

    f32x4 acc[4][4];
#pragma unroll
    for (int i = 0; i < 4; ++i)
#pragma unroll
        for (int j = 0; j < 4; ++j) acc[i][j] = (f32x4)0.f;

    const int lane = tid & 63;
    const int row = lane & 15;
    const int quad = lane >> 4;
    const int wv = tid >> 6;
    const int wm = (wv & 1) * 64;
    const int wn = (wv >> 1) * 64;
    const int octb = (n0 + wn) >> 4;

    for (int kb = 0; kb < nKb; ++kb) {
        int koff;
        if (KHW == 9) {
            // C == 256: 2 sub-blocks of 128 channels per (ky,kx)
            int pos = kb >> 1;
            int cin0 = (kb & 1) << 7;
            int ky = pos / 3;
            int kx = pos - ky * 3;
            koff = (ky * W + kx) * C + cin0;
        } else {
            koff = kb << 7;
        }
#pragma unroll
        for (int s = 0; s < 8; ++s)
            async_copy16(&sA[tid * 8 + s * 2048], A + abase[s] + koff);

        // B fragments: issue before the barrier so latency rides the drain.
        f16x8 bh[4][4];
#pragma unroll
        for (int ks = 0; ks < 4; ++ks)
#pragma unroll
            for (int j = 0; j < 4; ++j)
                bh[ks][j] = *(const f16x8*)&Bp[((size_t)(octb + j) * nK32 +
                                               kb * 4 + ks) *
                                                  512 +
                                              lane * 8];
        __syncthreads();

#pragma unroll
        for (int ks = 0; ks < 4; ++ks) {
            f16x8 ah[4];
#pragma unroll
            for (int i = 0; i < 4; ++i) {
                int g = wm + i * 16 + row;
                ah[i] =
                    *(const f16x8*)&sA[g * 128 +
                                       ((((ks << 2) | quad) ^ row) << 3)];
            }
#pragma unroll
            for (int i = 0; i < 4; ++i)
#pragma unroll
                for (int j = 0; j < 4; ++j)
                    acc[i][j] = __builtin_amdgcn_mfma_f32_16x16x32_f16(
                        ah[i], bh[ks][j], acc[i][j], 0, 0, 0);
        }
        __syncthreads();
    }

    // Epilogue. C/D layout: col(n) = lane&15, row(m) = quad*4 + reg.
#pragma unroll
    for (int j = 0; j < 4; ++j) {
        int oc = n0 + wn + j * 16 + row;
        bool ocv = oc < OC;
        float scale = 1.f, shift = 0.f;
        if (ocv) {
            if (EPI != 3) {
                float g = bnp[oc];
                float bb = bnp[OC + oc];
                float mm = bnp[2 * OC + oc];
                float vv = bnp[3 * OC + oc];
                float inv = g * rsqrtf(vv + EPSBN);
                scale = inv;
                shift = bb - mm * inv;
            } else {
                shift = bnp[oc];  // bias
            }
        }
#pragma unroll
        for (int i = 0; i < 4; ++i) {
#pragma unroll
            for (int r = 0; r < 4; ++r) {
                int m = m0 + wm + i * 16 + quad * 4 + r;
                if (m < M && ocv) {
                    float v = acc[i][j][r] * scale + shift;
                    if (EPI == 2) v = fmaxf(v, 0.f);
                    if (EPI == 3) {
                        int b = m / OHW;
                        int rr = m - b * OHW;
                        outF[((size_t)b * OC + oc) * OHW + rr] = v;
                    } else {
                        oF[(size_t)m * OC + oc] = (f16)v;
                    }
                }
            }
        }
    }
}

// Fused conv3x3: search (x-blocks [0,421)) and kernel (x-blocks [421,434)).
__global__ __launch_bounds__(256, 3) void conv33_fused(
    const f16* sA_g, const f16* bpS, const float* bns, f16* sOut,
    const f16* kA_g, const f16* bpK, const float* bnk, f16* kOut) {
    __shared__ f16 sA[16384];
    bool sec = blockIdx.x >= 421;
    const f16* A = sec ? kA_g : sA_g;
    const f16* Bp = sec ? bpK : bpS;
    const float* bnp = sec ? bnk : bns;
    f16* oF = sec ? kOut : sOut;
    int M = sec ? 1600 : 53824;
    int H = sec ? 7 : 31;
    int OHs = sec ? 5 : 29;
    int m0 = (blockIdx.x - (sec ? 421 : 0)) * 128;
    int n0 = blockIdx.y * 128;
    gemm_body<9, 2>(sA, A, Bp, bnp, nullptr, oF, m0, n0, M, 256, 256, H, H,
                    OHs, OHs);
}

template <int EPI>
__global__ __launch_bounds__(256, 3) void gemm_1x1(
    const f16* __restrict__ A, const f16* __restrict__ Bp,
    const float* __restrict__ bnp, float* __restrict__ outF,
    f16* __restrict__ oF, int M, int OC, int C) {
    __shared__ f16 sA[16384];
    gemm_body<1, EPI>(sA, A, Bp, bnp, outF, oF, blockIdx.x * 128,
                      blockIdx.y * 128, M, OC, C, 25, 25, 25, 25);
}

// ---------------------------------------------------------------------------
// Multi-scale depthwise xcorr, NHWC f16 in, f16 NHWC out (f32 accumulate).
// Sliding 5x5 window: 5 fresh loads per x instead of 25.
// ---------------------------------------------------------------------------
__global__ __launch_bounds__(256) void xcorr_nhwc(
    const f16* __restrict__ sf, const f16* __restrict__ kf,
    f16* __restrict__ feat) {
    int by = blockIdx.x;  // b*25 + y
    int b = by / 25;
    int y = by - b * 25;
    int c = threadIdx.x;  // 0..255
    float kv[25];
#pragma unroll
    for (int p = 0; p < 25; ++p)
        kv[p] = (float)kf[(size_t)(b * 25 + p) * 256 + c];
    const f16* srow = sf + (size_t)(b * 29 + y) * 29 * 256 + c;
    float sv[25];
#pragma unroll
    for (int d = 0; d < 5; ++d)
#pragma unroll
        for (int e = 0; e < 5; ++e)
            sv[d * 5 + e] = (float)srow[(size_t)(d * 29 + e) * 256];
    for (int x = 0;; ++x) {
        float a0 = 0.f, a1 = 0.f, a2;
#pragma unroll
        for (int p = 0; p < 25; ++p) a0 = fmaf(sv[p], kv[p], a0);
#pragma unroll
        for (int d = 1; d < 4; ++d)
#pragma unroll
            for (int e = 1; e < 4; ++e)
                a1 = fmaf(sv[d * 5 + e], kv[d * 5 + e], a1);
        a2 = sv[12] * kv[12];
        size_t o = ((size_t)by * 25 + x) * 768 + c;
        feat[o] = (f16)a0;
        feat[o + 256] = (f16)a1;
        feat[o + 512] = (f16)a2;
        if (x == 24) break;
#pragma unroll
        for (int d = 0; d < 5; ++d) {
#pragma unroll
            for (int e = 0; e < 4; ++e) sv[d * 5 + e] = sv[d * 5 + e + 1];
            sv[d * 5 + 4] = (float)srow[(size_t)(d * 29 + x + 5) * 256];
        }
    }
}

// ---------------------------------------------------------------------------
extern "C" void kernel_launch(void* const* d_in, const int* in_sizes, int n_in,
                              void* d_out, int out_size, void* d_ws,
                              size_t ws_size, hipStream_t stream) {
    const float* kernel_in = (const float*)d_in[0];  // (64,256,7,7)
    const float* search_in = (const float*)d_in[1];  // (64,256,31,31)
    const float* wk = (const float*)d_in[2];         // (256,256,3,3)
    const float* bnk = (const float*)d_in[3];
    const float* ws = (const float*)d_in[4];
    const float* bns = (const float*)d_in[5];
    const float* wd = (const float*)d_in[6];  // (256,768)
    const float* bnd = (const float*)d_in[7];
    const float* wh1 = (const float*)d_in[8];  // (256,256)
    const float* bnh = (const float*)d_in[9];
    const float* wh2 = (const float*)d_in[10];  // (10,256)
    const float* bh2 = (const float*)d_in[11];  // (10,)
    float* out = (float*)d_out;                 // (64,10,25,25) NCHW

    char* base = (char*)d_ws;
    size_t off = 0;
    auto alloc = [&](size_t bytes) {
        off = (off + 511) & ~(size_t)511;
        void* p = base + off;
        off += bytes;
        return p;
    };

    // Persistent region
    f16* bpd = (f16*)alloc((size_t)16 * 24 * 512 * 2);  // wd frags
    f16* bp1 = (f16*)alloc((size_t)16 * 8 * 512 * 2);   // wh1 frags
    f16* bp2 = (f16*)alloc((size_t)8 * 8 * 512 * 2);    // wh2 frags (padded)
    size_t Pf = (off + 511) & ~(size_t)511;  // f2 aliases here later
    f16* kfeat = (f16*)alloc((size_t)1600 * 256 * 2);
    f16* sfeat = (f16*)alloc((size_t)53824 * 256 * 2);
    size_t P1 = (off + 511) & ~(size_t)511;  // feat/hbuf alias here
    // Transients (dead after conv33_fused)
    f16* bpk = (f16*)alloc((size_t)16 * 72 * 512 * 2);
    f16* bps = (f16*)alloc((size_t)16 * 72 * 512 * 2);
    f16* ka = (f16*)alloc((size_t)64 * 49 * 256 * 2);
    f16* sa = (f16*)alloc((size_t)64 * 961 * 256 * 2);
    // Aliases
    f16* feat = (f16*)(base + P1);  // 40000*768 (over dead transients+free)
    f16* f2 = (f16*)(base + Pf);    // 40000*256 (kfeat/sfeat dead)
    f16* hb = (f16*)(base + P1);    // 40000*256 (feat dead)

    // 1) activation transpose->f16 NHWC + all weight fragment packs
    //    grid = 4352 transpose + (2304+2304+768+256+128)=5760 weight blocks
    prep_all<<<dim3(10112), 256, 0, stream>>>(search_in, sa, kernel_in, ka,
                                              wk, ws, wd, wh1, wh2, bpk, bps,
                                              bpd, bp1, bp2);
    // 2) fused conv3x3 (search + kernel) -> f16 NHWC
    conv33_fused<<<dim3(434, 2), 256, 0, stream>>>(sa, bps, bns, sfeat, ka,
                                                   bpk, bnk, kfeat);
    // 3) xcorr -> feat f16 NHWC [40000][768]
    xcorr_nhwc<<<dim3(1600), 256, 0, stream>>>(sfeat, kfeat, feat);
    // 4) wd: 1x1, K=768, BN -> f2 f16
    gemm_1x1<1><<<dim3(313, 2), 256, 0, stream>>>(feat, bpd, bnd, nullptr, f2,
                                                  40000, 256, 768);
    // 5) wh1: 1x1, K=256, BN+ReLU -> hb f16
    gemm_1x1<2><<<dim3(313, 2), 256, 0, stream>>>(f2, bp1, bnh, nullptr, hb,
                                                  40000, 256, 256);
    // 6) wh2: 1x1, K=256, +bias -> out f32 NCHW
    gemm_1x1<3><<<dim3(313, 1), 256, 0, stream>>>(hb, bp2, bh2, out, nullptr,
                                                  40000, 10, 256);
}

// Round 8
// 330.202 us; speedup vs baseline: 7.9695x; 1.0064x over previous
//
#include <hip/hip_runtime.h>
#include <hip/hip_bf16.h>
#include <cstdint>
#include <cstddef>

#define EPSBN 1e-5f

typedef unsigned short u16;
typedef unsigned int u32;
typedef _Float16 f16;
typedef _Float16 f16x8 __attribute__((ext_vector_type(8)));
typedef float f32x4 __attribute__((ext_vector_type(4)));

// async global->LDS, 16B per lane
__device__ __forceinline__ void async_copy16(void* lds, const void* g) {
    __builtin_amdgcn_global_load_lds(
        (const __attribute__((address_space(1))) u32*)g,
        (__attribute__((address_space(3))) u32*)lds, 16, 0, 0);
}

// ---------------------------------------------------------------------------
// One prep kernel:
//  blocks [0,4352): NCHW f32 -> NHWC f16 transpose (search + kernel acts)
//  blocks [4352,...): weight fragment packing, f16:
//    Bp[oct][k32][lane][j] = W[oct*16+(lane&15)][k32*32+(lane>>4)*8+j]
//    3x3 convs use k = pos*256+cin (matches A im2col order).
//    ranges (blocks): wk 2304 | ws 2304 | wd 768 | wh1 256 | wh2 128
// ---------------------------------------------------------------------------
__global__ __launch_bounds__(256) void prep_all(
    const float* __restrict__ sin, f16* __restrict__ sa,
    const float* __restrict__ kin, f16* __restrict__ ka,
    const float* __restrict__ wk, const float* __restrict__ ws,
    const float* __restrict__ wd, const float* __restrict__ wh1,
    const float* __restrict__ wh2, f16* __restrict__ bpk,
    f16* __restrict__ bps, f16* __restrict__ bpd, f16* __restrict__ bp1,
    f16* __restrict__ bp2) {
    __shared__ float tile[64][65];
    int t = blockIdx.x;
    int tid = threadIdx.x;
    if (t < 4352) {  // 64 b x 4 ctiles x 17 z
        int b = t / 68;
        int rem = t - b * 68;
        int c0 = (rem / 17) * 64;
        int z = rem % 17;
        bool isk = (z == 16);
        const float* in = isk ? kin : sin;
        f16* op = isk ? ka : sa;
        int HW = isk ? 49 : 961;
        int h0 = isk ? 0 : z * 64;
        int cl = tid >> 6;
        int hl = tid & 63;
        for (int r = cl; r < 64; r += 4) {
            int hw = h0 + hl;
            tile[r][hl] =
                (hw < HW) ? in[(size_t)(b * 256 + c0 + r) * HW + hw] : 0.f;
        }
        __syncthreads();
        int c = tid & 63;
        for (int r = cl; r < 64; r += 4) {
            int hw = h0 + r;
            if (hw < HW)
                op[((size_t)b * HW + hw) * 256 + c0 + c] = (f16)tile[c][r];
        }
        return;
    }
    int blk = t - 4352;
    const float* W;
    f16* Bp;
    int nK32, OCr, K, i;
    bool conv = false;
    if (blk < 2304) {
        W = wk; Bp = bpk; nK32 = 72; OCr = 256; K = 2304; conv = true;
        i = blk * 256 + tid;
    } else if (blk < 4608) {
        W = ws; Bp = bps; nK32 = 72; OCr = 256; K = 2304; conv = true;
        i = (blk - 2304) * 256 + tid;
    } else if (blk < 5376) {  // wd: 16 octs * 24 k32 * 512 = 768 blocks
        W = wd; Bp = bpd; nK32 = 24; OCr = 256; K = 768;
        i = (blk - 4608) * 256 + tid;
    } else if (blk < 5632) {
        W = wh1; Bp = bp1; nK32 = 8; OCr = 256; K = 256;
        i = (blk - 5376) * 256 + tid;
    } else {
        W = wh2; Bp = bp2; nK32 = 8; OCr = 10; K = 256;
        i = (blk - 5632) * 256 + tid;
    }
    int per = nK32 * 512;
    int oct = i / per;
    int r = i - oct * per;
    int k32 = r >> 9;
    int lr = r & 511;
    int l = lr >> 3, j = lr & 7;
    int oc = oct * 16 + (l & 15);
    int k = k32 * 32 + ((l >> 4) << 3) + j;
    float v = 0.f;
    if (oc < OCr)
        v = conv ? W[(size_t)(oc * 256 + (k & 255)) * 9 + (k >> 8)]
                 : W[(size_t)oc * K + k];
    Bp[(size_t)(oct * nK32 + k32) * 512 + lr] = (f16)v;
}

// ---------------------------------------------------------------------------
// f16 MFMA GEMM, double-buffered:
//  - A staged in LDS, BK=128 windows, two 32KB buffers (XOR-swizzled chunks)
//  - B fragments prepacked in global, prefetched into alternate reg sets
//  - after each barrier: issue window k+1's loads, then compute window k,
//    so the barrier's vmcnt drain only covers (latency - compute) residue.
// BM=BN=128, 256 thr, 4 waves (2m x 2n), each 64x64 via 4x4 16x16x32 MFMA.
// nKb must be even (18 / 6 / 2 here).
// EPI: 1 BN->f16 NHWC; 2 BN+ReLU->f16 NHWC; 3 +bias->f32 NCHW.
// ---------------------------------------------------------------------------
template <int KHW, int EPI>
__device__ __forceinline__ void gemm_body(
    f16* sA, const f16* __restrict__ A, const f16* __restrict__ Bp,
    const float* __restrict__ bnp, float* __restrict__ outF,
    f16* __restrict__ oF, int m0, int n0, int M, int OC, int C, int H, int W,
    int OH, int OW) {
    const int Ktot = KHW * C;
    const int nKb = Ktot >> 7;   // 128-wide K windows (even)
    const int nK32 = Ktot >> 5;  // Bp granularity
    const int tid = threadIdx.x;
    const int OHW = OH * OW;

    // A staging: 128 rows x 128 k x 2B = 32KB per buffer; 2048 16B chunks.
    // LDS[ml][q] holds global chunk q ^ (ml&15) (read-side bank spread).
    int abase[8];
#pragma unroll
    for (int s = 0; s < 8; ++s) {
        int idx = tid + s * 256;
        int ml = idx >> 4;
        int qs = (idx & 15) ^ (ml & 15);
        int m = m0 + ml;
        if (m >= M) m = M - 1;
        int b = m / OHW;
        int r = m - b * OHW;
        int y = r / OW;
        int x = r - y * OW;
        abase[s] = ((b * H + y) * W + x) * C + qs * 8;
    }

    f32x4 acc[4][4];
#pragma unroll
    for (int i = 0; i < 4; ++i)
#pragma unroll
        for (int j = 0; j < 4; ++j) acc[i][j] = (f32x4)0.f;

    const int lane = tid & 63;
    const int row = lane & 15;
    const int quad = lane >> 4;
    const int wv = tid >> 6;
    const int wm = (wv & 1) * 64;
    const int wn = (wv >> 1) * 64;
    const int octb = (n0 + wn) >> 4;

    auto koff_of = [&](int kb) {
        if (KHW == 9) {
            int pos = kb >> 1;
            int cin0 = (kb & 1) << 7;
            int ky = pos / 3;
            int kx = pos - ky * 3;
            return (ky * W + kx) * C + cin0;
        }
        return kb << 7;
    };
    auto issueA = [&](int bufbase, int kb) {
        int koff = koff_of(kb);
#pragma unroll
        for (int s = 0; s < 8; ++s)
            async_copy16(&sA[bufbase + tid * 8 + s * 2048],
                         A + abase[s] + koff);
    };
    auto loadB = [&](f16x8(&bh)[4][4], int kb) {
#pragma unroll
        for (int ks = 0; ks < 4; ++ks)
#pragma unroll
            for (int j = 0; j < 4; ++j)
                bh[ks][j] =
                    *(const f16x8*)&Bp[((size_t)(octb + j) * nK32 + kb * 4 +
                                        ks) *
                                           512 +
                                       lane * 8];
    };
    auto compute = [&](int bufbase, f16x8(&bh)[4][4]) {
#pragma unroll
        for (int ks = 0; ks < 4; ++ks) {
            f16x8 ah[4];
#pragma unroll
            for (int i = 0; i < 4; ++i) {
                int g = wm + i * 16 + row;
                ah[i] = *(const f16x8*)&sA[bufbase + g * 128 +
                                           ((((ks << 2) | quad) ^ row) << 3)];
            }
#pragma unroll
            for (int i = 0; i < 4; ++i)
#pragma unroll
                for (int j = 0; j < 4; ++j)
                    acc[i][j] = __builtin_amdgcn_mfma_f32_16x16x32_f16(
                        ah[i], bh[ks][j], acc[i][j], 0, 0, 0);
        }
    };

    f16x8 bh0[4][4], bh1[4][4];
    issueA(0, 0);
    loadB(bh0, 0);
    for (int kb = 0; kb < nKb; kb += 2) {
        __syncthreads();  // buf0 A landed; all waves done reading buf1
        issueA(16384, kb + 1);
        loadB(bh1, kb + 1);
        compute(0, bh0);
        __syncthreads();  // buf1 A landed; all waves done reading buf0
        if (kb + 2 < nKb) {
            issueA(0, kb + 2);
            loadB(bh0, kb + 2);
        }
        compute(16384, bh1);
    }

    // Epilogue. C/D layout: col(n) = lane&15, row(m) = quad*4 + reg.
#pragma unroll
    for (int j = 0; j < 4; ++j) {
        int oc = n0 + wn + j * 16 + row;
        bool ocv = oc < OC;
        float scale = 1.f, shift = 0.f;
        if (ocv) {
            if (EPI != 3) {
                float g = bnp[oc];
                float bb = bnp[OC + oc];
                float mm = bnp[2 * OC + oc];
                float vv = bnp[3 * OC + oc];
                float inv = g * rsqrtf(vv + EPSBN);
                scale = inv;
                shift = bb - mm * inv;
            } else {
                shift = bnp[oc];  // bias
            }
        }
#pragma unroll
        for (int i = 0; i < 4; ++i) {
#pragma unroll
            for (int r = 0; r < 4; ++r) {
                int m = m0 + wm + i * 16 + quad * 4 + r;
                if (m < M && ocv) {
                    float v = acc[i][j][r] * scale + shift;
                    if (EPI == 2) v = fmaxf(v, 0.f);
                    if (EPI == 3) {
                        int b = m / OHW;
                        int rr = m - b * OHW;
                        outF[((size_t)b * OC + oc) * OHW + rr] = v;
                    } else {
                        oF[(size_t)m * OC + oc] = (f16)v;
                    }
                }
            }
        }
    }
}

// Fused conv3x3: kernel branch first (x<13: starts early, no tail straggle),
// search branch x-blocks [13,434).
__global__ __launch_bounds__(256, 2) void conv33_fused(
    const f16* sA_g, const f16* bpS, const float* bns, f16* sOut,
    const f16* kA_g, const f16* bpK, const float* bnk, f16* kOut) {
    __shared__ f16 sA[32768];
    bool sec = blockIdx.x < 13;
    const f16* A = sec ? kA_g : sA_g;
    const f16* Bp = sec ? bpK : bpS;
    const float* bnp = sec ? bnk : bns;
    f16* oF = sec ? kOut : sOut;
    int M = sec ? 1600 : 53824;
    int H = sec ? 7 : 31;
    int OHs = sec ? 5 : 29;
    int m0 = (sec ? blockIdx.x : (blockIdx.x - 13)) * 128;
    int n0 = blockIdx.y * 128;
    gemm_body<9, 2>(sA, A, Bp, bnp, nullptr, oF, m0, n0, M, 256, 256, H, H,
                    OHs, OHs);
}

template <int EPI>
__global__ __launch_bounds__(256, 2) void gemm_1x1(
    const f16* __restrict__ A, const f16* __restrict__ Bp,
    const float* __restrict__ bnp, float* __restrict__ outF,
    f16* __restrict__ oF, int M, int OC, int C) {
    __shared__ f16 sA[32768];
    gemm_body<1, EPI>(sA, A, Bp, bnp, outF, oF, blockIdx.x * 128,
                      blockIdx.y * 128, M, OC, C, 25, 25, 25, 25);
}

// ---------------------------------------------------------------------------
// Multi-scale depthwise xcorr, NHWC f16 in, f16 NHWC out (f32 accumulate).
// Sliding 5x5 window: 5 fresh loads per x instead of 25.
// ---------------------------------------------------------------------------
__global__ __launch_bounds__(256) void xcorr_nhwc(
    const f16* __restrict__ sf, const f16* __restrict__ kf,
    f16* __restrict__ feat) {
    int by = blockIdx.x;  // b*25 + y
    int b = by / 25;
    int y = by - b * 25;
    int c = threadIdx.x;  // 0..255
    float kv[25];
#pragma unroll
    for (int p = 0; p < 25; ++p)
        kv[p] = (float)kf[(size_t)(b * 25 + p) * 256 + c];
    const f16* srow = sf + (size_t)(b * 29 + y) * 29 * 256 + c;
    float sv[25];
#pragma unroll
    for (int d = 0; d < 5; ++d)
#pragma unroll
        for (int e = 0; e < 5; ++e)
            sv[d * 5 + e] = (float)srow[(size_t)(d * 29 + e) * 256];
    for (int x = 0;; ++x) {
        float a0 = 0.f, a1 = 0.f, a2;
#pragma unroll
        for (int p = 0; p < 25; ++p) a0 = fmaf(sv[p], kv[p], a0);
#pragma unroll
        for (int d = 1; d < 4; ++d)
#pragma unroll
            for (int e = 1; e < 4; ++e)
                a1 = fmaf(sv[d * 5 + e], kv[d * 5 + e], a1);
        a2 = sv[12] * kv[12];
        size_t o = ((size_t)by * 25 + x) * 768 + c;
        feat[o] = (f16)a0;
        feat[o + 256] = (f16)a1;
        feat[o + 512] = (f16)a2;
        if (x == 24) break;
#pragma unroll
        for (int d = 0; d < 5; ++d) {
#pragma unroll
            for (int e = 0; e < 4; ++e) sv[d * 5 + e] = sv[d * 5 + e + 1];
            sv[d * 5 + 4] = (float)srow[(size_t)(d * 29 + x + 5) * 256];
        }
    }
}

// ---------------------------------------------------------------------------
extern "C" void kernel_launch(void* const* d_in, const int* in_sizes, int n_in,
                              void* d_out, int out_size, void* d_ws,
                              size_t ws_size, hipStream_t stream) {
    const float* kernel_in = (const float*)d_in[0];  // (64,256,7,7)
    const float* search_in = (const float*)d_in[1];  // (64,256,31,31)
    const float* wk = (const float*)d_in[2];         // (256,256,3,3)
    const float* bnk = (const float*)d_in[3];
    const float* ws = (const float*)d_in[4];
    const float* bns = (const float*)d_in[5];
    const float* wd = (const float*)d_in[6];  // (256,768)
    const float* bnd = (const float*)d_in[7];
    const float* wh1 = (const float*)d_in[8];  // (256,256)
    const float* bnh = (const float*)d_in[9];
    const float* wh2 = (const float*)d_in[10];  // (10,256)
    const float* bh2 = (const float*)d_in[11];  // (10,)
    float* out = (float*)d_out;                 // (64,10,25,25) NCHW

    char* base = (char*)d_ws;
    size_t off = 0;
    auto alloc = [&](size_t bytes) {
        off = (off + 511) & ~(size_t)511;
        void* p = base + off;
        off += bytes;
        return p;
    };

    // Persistent region
    f16* bpd = (f16*)alloc((size_t)16 * 24 * 512 * 2);  // wd frags
    f16* bp1 = (f16*)alloc((size_t)16 * 8 * 512 * 2);   // wh1 frags
    f16* bp2 = (f16*)alloc((size_t)8 * 8 * 512 * 2);    // wh2 frags (padded)
    size_t Pf = (off + 511) & ~(size_t)511;  // f2 aliases here later
    f16* kfeat = (f16*)alloc((size_t)1600 * 256 * 2);
    f16* sfeat = (f16*)alloc((size_t)53824 * 256 * 2);
    size_t P1 = (off + 511) & ~(size_t)511;  // feat/hbuf alias here
    // Transients (dead after conv33_fused)
    f16* bpk = (f16*)alloc((size_t)16 * 72 * 512 * 2);
    f16* bps = (f16*)alloc((size_t)16 * 72 * 512 * 2);
    f16* ka = (f16*)alloc((size_t)64 * 49 * 256 * 2);
    f16* sa = (f16*)alloc((size_t)64 * 961 * 256 * 2);
    // Aliases
    f16* feat = (f16*)(base + P1);  // 40000*768 (over dead transients+free)
    f16* f2 = (f16*)(base + Pf);    // 40000*256 (kfeat/sfeat dead)
    f16* hb = (f16*)(base + P1);    // 40000*256 (feat dead)

    // 1) activation transpose->f16 NHWC + all weight fragment packs
    //    grid = 4352 transpose + (2304+2304+768+256+128)=5760 weight blocks
    prep_all<<<dim3(10112), 256, 0, stream>>>(search_in, sa, kernel_in, ka,
                                              wk, ws, wd, wh1, wh2, bpk, bps,
                                              bpd, bp1, bp2);
    // 2) fused conv3x3 (kernel + search) -> f16 NHWC
    conv33_fused<<<dim3(434, 2), 256, 0, stream>>>(sa, bps, bns, sfeat, ka,
                                                   bpk, bnk, kfeat);
    // 3) xcorr -> feat f16 NHWC [40000][768]
    xcorr_nhwc<<<dim3(1600), 256, 0, stream>>>(sfeat, kfeat, feat);
    // 4) wd: 1x1, K=768, BN -> f2 f16
    gemm_1x1<1><<<dim3(313, 2), 256, 0, stream>>>(feat, bpd, bnd, nullptr, f2,
                                                  40000, 256, 768);
    // 5) wh1: 1x1, K=256, BN+ReLU -> hb f16
    gemm_1x1<2><<<dim3(313, 2), 256, 0, stream>>>(f2, bp1, bnh, nullptr, hb,
                                                  40000, 256, 256);
    // 6) wh2: 1x1, K=256, +bias -> out f32 NCHW
    gemm_1x1<3><<<dim3(313, 1), 256, 0, stream>>>(hb, bp2, bh2, out, nullptr,
                                                  40000, 10, 256);
}